// Round 5
// baseline (602.098 us; speedup 1.0000x reference)
//
#include <hip/hip_runtime.h>

typedef unsigned short ushort_t;
typedef unsigned int u32;
typedef _Float16 f16;
typedef f16 f16x8 __attribute__((ext_vector_type(8)));
typedef ushort_t u16x8 __attribute__((ext_vector_type(8)));
typedef float f32x4 __attribute__((ext_vector_type(4)));

#define C_DIM 256
#define HW 4096
#define CHW (C_DIM*HW)

// Device-global scratch (no d_ws dependence). Internal pipeline is f16 always.
__device__ __align__(16) f16 g_xbT[4 * CHW];
__device__ __align__(16) f16 g_q[4 * CHW];
__device__ __align__(16) f16 g_k[4 * CHW];
__device__ __align__(16) f16 g_v[4 * CHW];
__device__ int g_mode[1];   // 0 = inputs bf16, 1 = inputs f32

__device__ __forceinline__ float bf2f(ushort_t h) {
    union { u32 u; float f; } v; v.u = ((u32)h) << 16; return v.f;
}
__device__ __forceinline__ ushort_t f2bf(float f) {
    union { float f; u32 u; } v; v.f = f;
    u32 r = v.u + 0x7FFF + ((v.u >> 16) & 1);
    return (ushort_t)(r >> 16);
}
// finite-or-zero (NaN-safe: comparisons false for NaN)
__device__ __forceinline__ float fin0(float v) {
    return (v > -1e30f && v < 1e30f) ? v : 0.f;
}
// sanitize to f16 (clamp non-finite / huge to 0)
__device__ __forceinline__ f16 sf16(float v) {
    return (f16)((v > -1e4f && v < 1e4f) ? v : 0.f);
}

// ---------------- kernel 0: dtype probe ----------------
__global__ void k_probe(const void* __restrict__ xv) {
    const ushort_t* xh = (const ushort_t*)xv;
    int lane = threadIdx.x;
    float s = 0.f;
    for (int i = lane; i < 2048; i += 64) {
        float v = fabsf(bf2f(xh[i]));
        v = (v < 1e6f) ? v : 1e6f;   // NaN/Inf -> 1e6 (NaN-safe)
        s += v;
    }
#pragma unroll
    for (int d = 1; d < 64; d <<= 1) s += __shfl_xor(s, d, 64);
    if (lane == 0) g_mode[0] = (s * (1.f / 2048.f) > 100.f) ? 1 : 0;
}

// ---------------- sentinel: distinctive fill if host-side assumptions fail ----------------
__global__ void k_sentinel(ushort_t* out, int n) {
    int i = blockIdx.x * 256 + threadIdx.x;
    if (i < n) out[i] = f2bf(777.f);
}

// ---------------- kernel 1: x (N,C,HW) [bf16 or f32] -> g_xbT f16 (N,HW,C) ----------------
__global__ __launch_bounds__(256) void k_transpose(const void* __restrict__ xv) {
    __shared__ f16 t[64][66];
    int mode = g_mode[0];
    int n = blockIdx.z, c0 = blockIdx.y * 64, l0 = blockIdx.x * 64;
    int tid = threadIdx.x;
    f16* ob = g_xbT + n * CHW;
    int lq = (tid & 15) * 4;
    int cl = tid >> 4;
    if (mode == 0) {
        const ushort_t* xb = (const ushort_t*)xv + n * CHW;
#pragma unroll
        for (int p = 0; p < 4; ++p) {
            int c = cl + 16 * p;
            ushort4 v = *(const ushort4*)(xb + (c0 + c) * HW + l0 + lq);
            t[lq + 0][c] = sf16(bf2f(v.x));
            t[lq + 1][c] = sf16(bf2f(v.y));
            t[lq + 2][c] = sf16(bf2f(v.z));
            t[lq + 3][c] = sf16(bf2f(v.w));
        }
    } else {
        const float* xb = (const float*)xv + n * CHW;
#pragma unroll
        for (int p = 0; p < 4; ++p) {
            int c = cl + 16 * p;
            float4 v = *(const float4*)(xb + (c0 + c) * HW + l0 + lq);
            t[lq + 0][c] = sf16(v.x);
            t[lq + 1][c] = sf16(v.y);
            t[lq + 2][c] = sf16(v.z);
            t[lq + 3][c] = sf16(v.w);
        }
    }
    __syncthreads();
    int c2 = (tid & 31) * 2;
    int lr = tid >> 5;
#pragma unroll
    for (int p = 0; p < 8; ++p) {
        int l = lr + 8 * p;
        u32 pair = *(const u32*)&t[l][c2];
        *(u32*)(ob + (l0 + l) * C_DIM + c0 + c2) = pair;
    }
}

// ---------------- kernel 2: projections (f16 MFMA) ----------------
__global__ __launch_bounds__(256) void k_proj(
    const void* __restrict__ Wq, const void* __restrict__ bq,
    const void* __restrict__ Wk, const void* __restrict__ bk,
    const void* __restrict__ Wv, const void* __restrict__ bv)
{
    __shared__ __align__(16) f16 lds_x[128 * 64];
    __shared__ __align__(16) f16 lds_w[128 * 64];
    int mode = g_mode[0];
    int l0 = blockIdx.x * 128;
    int og0 = blockIdx.y * 128;
    int n = blockIdx.z;
    int mat = og0 >> 8;       // 0=q,1=k,2=v
    int om0 = og0 & 255;
    const void* W = (mat == 0) ? Wq : (mat == 1) ? Wk : Wv;
    const void* bias = (mat == 0) ? bq : (mat == 1) ? bk : bv;
    int tid = threadIdx.x, w = tid >> 6, lane = tid & 63;
    int quad = lane >> 4, l16 = lane & 15;
    const f16* xb = g_xbT + n * CHW;

    f32x4 acc[2][8];
#pragma unroll
    for (int a = 0; a < 2; a++)
#pragma unroll
        for (int b = 0; b < 8; b++) acc[a][b] = f32x4{0.f, 0.f, 0.f, 0.f};

    for (int ch = 0; ch < 4; ++ch) {
        int cc0 = ch * 64;
        f16x8 xs[4], wsr[4];
#pragma unroll
        for (int ti = 0; ti < 4; ++ti) {
            int s = (w * 4 + ti) * 64 + lane;
            int row = s >> 3, gp = s & 7;
            xs[ti] = *(const f16x8*)(xb + (l0 + row) * C_DIM + cc0 + gp * 8);
            f16x8 h;
            if (mode == 0) {
                u16x8 wv = *(const u16x8*)((const ushort_t*)W + (om0 + row) * C_DIM + cc0 + gp * 8);
#pragma unroll
                for (int e = 0; e < 8; e++) h[e] = sf16(bf2f(wv[e]));
            } else {
                const float* wf = (const float*)W + (om0 + row) * C_DIM + cc0 + gp * 8;
#pragma unroll
                for (int e = 0; e < 8; e++) h[e] = sf16(wf[e]);
            }
            wsr[ti] = h;
        }
        __syncthreads();
#pragma unroll
        for (int ti = 0; ti < 4; ++ti) {
            int s = (w * 4 + ti) * 64 + lane;
            int row = s >> 3, gp = s & 7;
            int pos = gp ^ (row & 7);
            *(f16x8*)(lds_x + (row * 8 + pos) * 8) = xs[ti];
            *(f16x8*)(lds_w + (row * 8 + pos) * 8) = wsr[ti];
        }
        __syncthreads();
#pragma unroll
        for (int ks = 0; ks < 2; ++ks) {
            f16x8 af[2];
#pragma unroll
            for (int mt = 0; mt < 2; ++mt) {
                int row = w * 32 + mt * 16 + l16;
                int g = ks * 4 + quad;
                int pos = g ^ (row & 7);
                af[mt] = *(const f16x8*)(lds_x + (row * 8 + pos) * 8);
            }
#pragma unroll
            for (int nt = 0; nt < 8; ++nt) {
                int rowo = nt * 16 + l16;
                int g = ks * 4 + quad;
                int pos = g ^ (rowo & 7);
                f16x8 bfv = *(const f16x8*)(lds_w + (rowo * 8 + pos) * 8);
                if (mat < 2) {
                    acc[0][nt] = __builtin_amdgcn_mfma_f32_16x16x32_f16(af[0], bfv, acc[0][nt], 0, 0, 0);
                    acc[1][nt] = __builtin_amdgcn_mfma_f32_16x16x32_f16(af[1], bfv, acc[1][nt], 0, 0, 0);
                } else {
                    acc[0][nt] = __builtin_amdgcn_mfma_f32_16x16x32_f16(bfv, af[0], acc[0][nt], 0, 0, 0);
                    acc[1][nt] = __builtin_amdgcn_mfma_f32_16x16x32_f16(bfv, af[1], acc[1][nt], 0, 0, 0);
                }
            }
        }
        __syncthreads();
    }

    auto loadb = [&](int i) -> float {
        return mode ? ((const float*)bias)[i] : bf2f(((const ushort_t*)bias)[i]);
    };
    if (mat < 2) {
        f16* T = ((mat == 0) ? g_q : g_k) + n * CHW;
        float bvv[8];
#pragma unroll
        for (int nt = 0; nt < 8; nt++) bvv[nt] = loadb(om0 + nt * 16 + l16);
#pragma unroll
        for (int mt = 0; mt < 2; mt++)
#pragma unroll
            for (int nt = 0; nt < 8; nt++)
#pragma unroll
                for (int r = 0; r < 4; r++) {
                    int l = l0 + w * 32 + mt * 16 + quad * 4 + r;
                    int o = om0 + nt * 16 + l16;
                    T[l * C_DIM + o] = sf16(acc[mt][nt][r] + bvv[nt]);
                }
    } else {
        f16* T = g_v + n * CHW;
#pragma unroll
        for (int mt = 0; mt < 2; mt++)
#pragma unroll
            for (int nt = 0; nt < 8; nt++)
#pragma unroll
                for (int r = 0; r < 4; r++) {
                    int o = om0 + nt * 16 + quad * 4 + r;
                    int l = l0 + w * 32 + mt * 16 + l16;
                    T[o * HW + l] = sf16(acc[mt][nt][r] + loadb(o));
                }
    }
}

// ---------------- kernel 3: flash attention + residual ----------------
__global__ __launch_bounds__(256, 1) void k_attn(
    const void* __restrict__ xv,
    const void* __restrict__ gv, void* __restrict__ outv)
{
    __shared__ __align__(16) char smem[65536];
    int mode = g_mode[0];

    int bid = blockIdx.x;
    int g = bid >> 3, x8 = bid & 7;
    int n = x8 >> 1;
    int itq = g * 2 + (x8 & 1);
    int i0 = itq * 64;
    int tid = threadIdx.x, w = tid >> 6, lane = tid & 63;
    int quad = lane >> 4, l16 = lane & 15;

    const f16* Qb = g_q + n * CHW;
    const f16* Kb = g_k + n * CHW;
    const f16* Vb = g_v + n * CHW;
    float gam = mode ? ((const float*)gv)[0] : bf2f(((const ushort_t*)gv)[0]);
    gam = fin0(gam);
    f16* pb = (f16*)smem + w * 640;

    f16x8 qf[8];
    {
        const f16* qrow = Qb + (i0 + w * 16 + l16) * C_DIM;
#pragma unroll
        for (int kk = 0; kk < 8; kk++)
            qf[kk] = *(const f16x8*)(qrow + kk * 32 + quad * 8);
    }

    f32x4 o_acc[16];
#pragma unroll
    for (int i = 0; i < 16; i++) o_acc[i] = f32x4{0.f, 0.f, 0.f, 0.f};
    float m_[4] = {-1e30f, -1e30f, -1e30f, -1e30f};
    float l_[4] = {0.f, 0.f, 0.f, 0.f};

    const f16* krow = Kb + l16 * C_DIM + quad * 8;
    const f16* vbase = Vb + l16 * HW + quad * 8;

    f16x8 kreg[16];
#pragma unroll
    for (int kk = 0; kk < 8; kk++)
#pragma unroll
        for (int nt = 0; nt < 2; nt++)
            kreg[kk * 2 + nt] = *(const f16x8*)(krow + (nt * 16) * C_DIM + kk * 32);

    f16x8 vreg[16];

    for (int jt = 0; jt < 128; ++jt) {
        const f16* vp = vbase + jt * 32;
#pragma unroll
        for (int nt2 = 0; nt2 < 16; ++nt2)
            vreg[nt2] = *(const f16x8*)(vp + nt2 * 16 * HW);

        f32x4 s0 = {0.f, 0.f, 0.f, 0.f}, s1 = {0.f, 0.f, 0.f, 0.f};
#pragma unroll
        for (int kk = 0; kk < 8; kk++) {
            s0 = __builtin_amdgcn_mfma_f32_16x16x32_f16(qf[kk], kreg[kk * 2 + 0], s0, 0, 0, 0);
            s1 = __builtin_amdgcn_mfma_f32_16x16x32_f16(qf[kk], kreg[kk * 2 + 1], s1, 0, 0, 0);
        }
        // sanitize S (any non-finite -> -30000: becomes p=0)
#pragma unroll
        for (int r = 0; r < 4; r++) {
            s0[r] = (s0[r] > -1e30f && s0[r] < 1e30f) ? s0[r] : -30000.f;
            s1[r] = (s1[r] > -1e30f && s1[r] < 1e30f) ? s1[r] : -30000.f;
        }

        float mx[4];
#pragma unroll
        for (int r = 0; r < 4; r++) mx[r] = fmaxf(s0[r], s1[r]);
#pragma unroll
        for (int d = 1; d < 16; d <<= 1)
#pragma unroll
            for (int r = 0; r < 4; r++) mx[r] = fmaxf(mx[r], __shfl_xor(mx[r], d, 64));
        float al[4], rs[4], p0[4], p1[4];
#pragma unroll
        for (int r = 0; r < 4; r++) {
            float mn = fmaxf(m_[r], mx[r]);
            al[r] = __builtin_amdgcn_exp2f((m_[r] - mn) * 1.4426950408889634f);
            p0[r] = __builtin_amdgcn_exp2f((s0[r] - mn) * 1.4426950408889634f);
            p1[r] = __builtin_amdgcn_exp2f((s1[r] - mn) * 1.4426950408889634f);
            rs[r] = p0[r] + p1[r];
            m_[r] = mn;
        }
#pragma unroll
        for (int d = 1; d < 16; d <<= 1)
#pragma unroll
            for (int r = 0; r < 4; r++) rs[r] += __shfl_xor(rs[r], d, 64);
#pragma unroll
        for (int r = 0; r < 4; r++) l_[r] = l_[r] * al[r] + rs[r];
        float asum = al[0] + al[1] + al[2] + al[3];
        if (__any(asum < 3.9999f)) {
            f32x4 av; av[0] = al[0]; av[1] = al[1]; av[2] = al[2]; av[3] = al[3];
#pragma unroll
            for (int t = 0; t < 16; t++) o_acc[t] *= av;
        }

#pragma unroll
        for (int r = 0; r < 4; r++) {
            pb[(quad * 4 + r) * 40 + l16]      = (f16)p0[r];
            pb[(quad * 4 + r) * 40 + 16 + l16] = (f16)p1[r];
        }
        __syncthreads();
        f16x8 pf = *(const f16x8*)(pb + l16 * 40 + quad * 8);

        if (jt + 1 < 128) {
            const f16* kp = krow + (jt + 1) * 32 * C_DIM;
#pragma unroll
            for (int kk = 0; kk < 8; kk++)
#pragma unroll
                for (int nt = 0; nt < 2; nt++)
                    kreg[kk * 2 + nt] = *(const f16x8*)(kp + nt * 16 * C_DIM + kk * 32);
        }

#pragma unroll
        for (int nt2 = 0; nt2 < 16; ++nt2)
            o_acc[nt2] = __builtin_amdgcn_mfma_f32_16x16x32_f16(pf, vreg[nt2], o_acc[nt2], 0, 0, 0);
    }

    // ---- epilogue ----
    f32x4 invl;
#pragma unroll
    for (int r = 0; r < 4; r++) invl[r] = (l_[r] > 1e-30f) ? 1.0f / l_[r] : 0.f;
#pragma unroll
    for (int t = 0; t < 16; t++) o_acc[t] *= invl;
    __syncthreads();
    float* ob = (float*)(smem + w * 16384);
#pragma unroll
    for (int nt2 = 0; nt2 < 16; nt2++)
#pragma unroll
        for (int r = 0; r < 4; r++)
            ob[(nt2 * 16 + l16) * 16 + quad * 4 + r] = o_acc[nt2][r];
    __syncthreads();
    int ig = i0 + w * 16;
    if (mode == 0) {
        const ushort_t* xb = (const ushort_t*)xv + n * CHW;
        ushort_t* outb = (ushort_t*)outv + n * CHW;
#pragma unroll
        for (int rep = 0; rep < 32; ++rep) {
            int idx2 = rep * 128 + lane * 2;
            int c = idx2 >> 4, il = idx2 & 15;
            float o0 = ob[c * 16 + il], o1 = ob[c * 16 + il + 1];
            u32 xp = *(const u32*)(xb + c * HW + ig + il);
            float x0 = bf2f((ushort_t)(xp & 0xFFFF));
            float x1 = bf2f((ushort_t)(xp >> 16));
            u32 res = ((u32)f2bf(fin0(x1 + gam * o1)) << 16) | (u32)f2bf(fin0(x0 + gam * o0));
            *(u32*)(outb + c * HW + ig + il) = res;
        }
    } else {
        const float* xb = (const float*)xv + n * CHW;
        float* outb = (float*)outv + n * CHW;
#pragma unroll
        for (int rep = 0; rep < 32; ++rep) {
            int idx2 = rep * 128 + lane * 2;
            int c = idx2 >> 4, il = idx2 & 15;
            float o0 = ob[c * 16 + il], o1 = ob[c * 16 + il + 1];
            float2 xp = *(const float2*)(xb + c * HW + ig + il);
            float2 res;
            res.x = fin0(xp.x + gam * o0);
            res.y = fin0(xp.y + gam * o1);
            *(float2*)(outb + c * HW + ig + il) = res;
        }
    }
}

extern "C" void kernel_launch(void* const* d_in, const int* in_sizes, int n_in,
                              void* d_out, int out_size, void* d_ws, size_t ws_size,
                              hipStream_t stream) {
    (void)d_ws; (void)ws_size;
    bool ok = (n_in == 8) &&
              in_sizes[0] == 4 * CHW &&
              in_sizes[1] == C_DIM * C_DIM && in_sizes[2] == C_DIM &&
              in_sizes[3] == C_DIM * C_DIM && in_sizes[4] == C_DIM &&
              in_sizes[5] == C_DIM * C_DIM && in_sizes[6] == C_DIM &&
              in_sizes[7] == 1 && out_size == 4 * CHW;
    if (!ok) {
        hipLaunchKernelGGL(k_sentinel, dim3((out_size + 255) / 256), dim3(256), 0, stream,
                           (ushort_t*)d_out, out_size);
        return;
    }
    hipLaunchKernelGGL(k_probe, dim3(1), dim3(64), 0, stream, d_in[0]);
    hipLaunchKernelGGL(k_transpose, dim3(64, 4, 4), dim3(256), 0, stream, d_in[0]);
    hipLaunchKernelGGL(k_proj, dim3(32, 6, 4), dim3(256), 0, stream,
                       d_in[1], d_in[2], d_in[3], d_in[4], d_in[5], d_in[6]);
    hipLaunchKernelGGL(k_attn, dim3(256), dim3(256), 0, stream, d_in[0], d_in[7], d_out);
}

// Round 6
// 579.732 us; speedup vs baseline: 1.0386x; 1.0386x over previous
//
#include <hip/hip_runtime.h>

typedef unsigned short ushort_t;
typedef unsigned int u32;
typedef _Float16 f16;
typedef f16 f16x8 __attribute__((ext_vector_type(8)));
typedef ushort_t u16x8 __attribute__((ext_vector_type(8)));
typedef float f32x4 __attribute__((ext_vector_type(4)));

#define C_DIM 256
#define HW 4096
#define CHW (C_DIM*HW)

// Device-global scratch (no d_ws dependence). Internal pipeline is f16 always.
__device__ __align__(16) f16 g_xbT[4 * CHW];
__device__ __align__(16) f16 g_q[4 * CHW];
__device__ __align__(16) f16 g_k[4 * CHW];
__device__ __align__(16) f16 g_v[4 * CHW];
__device__ int g_mode[1];   // 0 = inputs bf16, 1 = inputs f32

__device__ __forceinline__ float bf2f(ushort_t h) {
    union { u32 u; float f; } v; v.u = ((u32)h) << 16; return v.f;
}
__device__ __forceinline__ ushort_t f2bf(float f) {
    union { float f; u32 u; } v; v.f = f;
    u32 r = v.u + 0x7FFF + ((v.u >> 16) & 1);
    return (ushort_t)(r >> 16);
}
__device__ __forceinline__ float fin0(float v) {
    return (v > -1e30f && v < 1e30f) ? v : 0.f;
}
__device__ __forceinline__ f16 sf16(float v) {
    return (f16)((v > -1e4f && v < 1e4f) ? v : 0.f);
}
__device__ __forceinline__ void gl2lds16(const f16* g, f16* l) {
    __builtin_amdgcn_global_load_lds(
        (const __attribute__((address_space(1))) u32*)g,
        (__attribute__((address_space(3))) u32*)l, 16, 0, 0);
}

// ---------------- kernel 0: dtype probe ----------------
__global__ void k_probe(const void* __restrict__ xv) {
    const ushort_t* xh = (const ushort_t*)xv;
    int lane = threadIdx.x;
    float s = 0.f;
    for (int i = lane; i < 2048; i += 64) {
        float v = fabsf(bf2f(xh[i]));
        v = (v < 1e6f) ? v : 1e6f;
        s += v;
    }
#pragma unroll
    for (int d = 1; d < 64; d <<= 1) s += __shfl_xor(s, d, 64);
    if (lane == 0) g_mode[0] = (s * (1.f / 2048.f) > 100.f) ? 1 : 0;
}

__global__ void k_sentinel(ushort_t* out, int n) {
    int i = blockIdx.x * 256 + threadIdx.x;
    if (i < n) out[i] = f2bf(777.f);
}

// ---------------- kernel 1: x (N,C,HW) -> g_xbT f16 (N,HW,C) ----------------
__global__ __launch_bounds__(256) void k_transpose(const void* __restrict__ xv) {
    __shared__ f16 t[64][66];
    int mode = g_mode[0];
    int n = blockIdx.z, c0 = blockIdx.y * 64, l0 = blockIdx.x * 64;
    int tid = threadIdx.x;
    f16* ob = g_xbT + n * CHW;
    int lq = (tid & 15) * 4;
    int cl = tid >> 4;
    if (mode == 0) {
        const ushort_t* xb = (const ushort_t*)xv + n * CHW;
#pragma unroll
        for (int p = 0; p < 4; ++p) {
            int c = cl + 16 * p;
            ushort4 v = *(const ushort4*)(xb + (c0 + c) * HW + l0 + lq);
            t[lq + 0][c] = sf16(bf2f(v.x));
            t[lq + 1][c] = sf16(bf2f(v.y));
            t[lq + 2][c] = sf16(bf2f(v.z));
            t[lq + 3][c] = sf16(bf2f(v.w));
        }
    } else {
        const float* xb = (const float*)xv + n * CHW;
#pragma unroll
        for (int p = 0; p < 4; ++p) {
            int c = cl + 16 * p;
            float4 v = *(const float4*)(xb + (c0 + c) * HW + l0 + lq);
            t[lq + 0][c] = sf16(v.x);
            t[lq + 1][c] = sf16(v.y);
            t[lq + 2][c] = sf16(v.z);
            t[lq + 3][c] = sf16(v.w);
        }
    }
    __syncthreads();
    int c2 = (tid & 31) * 2;
    int lr = tid >> 5;
#pragma unroll
    for (int p = 0; p < 8; ++p) {
        int l = lr + 8 * p;
        u32 pair = *(const u32*)&t[l][c2];
        *(u32*)(ob + (l0 + l) * C_DIM + c0 + c2) = pair;
    }
}

// ---------------- kernel 2: projections (f16 MFMA) ----------------
__global__ __launch_bounds__(256) void k_proj(
    const void* __restrict__ Wq, const void* __restrict__ bq,
    const void* __restrict__ Wk, const void* __restrict__ bk,
    const void* __restrict__ Wv, const void* __restrict__ bv)
{
    __shared__ __align__(16) f16 lds_x[128 * 64];
    __shared__ __align__(16) f16 lds_w[128 * 64];
    int mode = g_mode[0];
    int l0 = blockIdx.x * 128;
    int og0 = blockIdx.y * 128;
    int n = blockIdx.z;
    int mat = og0 >> 8;       // 0=q,1=k,2=v
    int om0 = og0 & 255;
    const void* W = (mat == 0) ? Wq : (mat == 1) ? Wk : Wv;
    const void* bias = (mat == 0) ? bq : (mat == 1) ? bk : bv;
    int tid = threadIdx.x, w = tid >> 6, lane = tid & 63;
    int quad = lane >> 4, l16 = lane & 15;
    const f16* xb = g_xbT + n * CHW;

    f32x4 acc[2][8];
#pragma unroll
    for (int a = 0; a < 2; a++)
#pragma unroll
        for (int b = 0; b < 8; b++) acc[a][b] = f32x4{0.f, 0.f, 0.f, 0.f};

    for (int ch = 0; ch < 4; ++ch) {
        int cc0 = ch * 64;
        f16x8 xs[4], wsr[4];
#pragma unroll
        for (int ti = 0; ti < 4; ++ti) {
            int s = (w * 4 + ti) * 64 + lane;
            int row = s >> 3, gp = s & 7;
            xs[ti] = *(const f16x8*)(xb + (l0 + row) * C_DIM + cc0 + gp * 8);
            f16x8 h;
            if (mode == 0) {
                u16x8 wv = *(const u16x8*)((const ushort_t*)W + (om0 + row) * C_DIM + cc0 + gp * 8);
#pragma unroll
                for (int e = 0; e < 8; e++) h[e] = sf16(bf2f(wv[e]));
            } else {
                const float* wf = (const float*)W + (om0 + row) * C_DIM + cc0 + gp * 8;
#pragma unroll
                for (int e = 0; e < 8; e++) h[e] = sf16(wf[e]);
            }
            wsr[ti] = h;
        }
        __syncthreads();
#pragma unroll
        for (int ti = 0; ti < 4; ++ti) {
            int s = (w * 4 + ti) * 64 + lane;
            int row = s >> 3, gp = s & 7;
            int pos = gp ^ (row & 7);
            *(f16x8*)(lds_x + (row * 8 + pos) * 8) = xs[ti];
            *(f16x8*)(lds_w + (row * 8 + pos) * 8) = wsr[ti];
        }
        __syncthreads();
#pragma unroll
        for (int ks = 0; ks < 2; ++ks) {
            f16x8 af[2];
#pragma unroll
            for (int mt = 0; mt < 2; ++mt) {
                int row = w * 32 + mt * 16 + l16;
                int g = ks * 4 + quad;
                int pos = g ^ (row & 7);
                af[mt] = *(const f16x8*)(lds_x + (row * 8 + pos) * 8);
            }
#pragma unroll
            for (int nt = 0; nt < 8; ++nt) {
                int rowo = nt * 16 + l16;
                int g = ks * 4 + quad;
                int pos = g ^ (rowo & 7);
                f16x8 bfv = *(const f16x8*)(lds_w + (rowo * 8 + pos) * 8);
                if (mat < 2) {
                    acc[0][nt] = __builtin_amdgcn_mfma_f32_16x16x32_f16(af[0], bfv, acc[0][nt], 0, 0, 0);
                    acc[1][nt] = __builtin_amdgcn_mfma_f32_16x16x32_f16(af[1], bfv, acc[1][nt], 0, 0, 0);
                } else {
                    acc[0][nt] = __builtin_amdgcn_mfma_f32_16x16x32_f16(bfv, af[0], acc[0][nt], 0, 0, 0);
                    acc[1][nt] = __builtin_amdgcn_mfma_f32_16x16x32_f16(bfv, af[1], acc[1][nt], 0, 0, 0);
                }
            }
        }
        __syncthreads();
    }

    auto loadb = [&](int i) -> float {
        return mode ? ((const float*)bias)[i] : bf2f(((const ushort_t*)bias)[i]);
    };
    if (mat < 2) {
        f16* T = ((mat == 0) ? g_q : g_k) + n * CHW;
        float bvv[8];
#pragma unroll
        for (int nt = 0; nt < 8; nt++) bvv[nt] = loadb(om0 + nt * 16 + l16);
#pragma unroll
        for (int mt = 0; mt < 2; mt++)
#pragma unroll
            for (int nt = 0; nt < 8; nt++)
#pragma unroll
                for (int r = 0; r < 4; r++) {
                    int l = l0 + w * 32 + mt * 16 + quad * 4 + r;
                    int o = om0 + nt * 16 + l16;
                    T[l * C_DIM + o] = sf16(acc[mt][nt][r] + bvv[nt]);
                }
    } else {
        f16* T = g_v + n * CHW;
#pragma unroll
        for (int mt = 0; mt < 2; mt++)
#pragma unroll
            for (int nt = 0; nt < 8; nt++)
#pragma unroll
                for (int r = 0; r < 4; r++) {
                    int o = om0 + nt * 16 + quad * 4 + r;
                    int l = l0 + w * 32 + mt * 16 + l16;
                    T[o * HW + l] = sf16(acc[mt][nt][r] + loadb(o));
                }
    }
}

// ---------------- kernel 3: flash attention, LDS-staged K/V, M=32/wave ----------------
__global__ __launch_bounds__(128, 1) void k_attn(
    const void* __restrict__ xv,
    const void* __restrict__ gv, void* __restrict__ outv)
{
    // smem: kbuf [2][1024 granules] 32KB | vbuf [2][1024] 32KB | pb 2 waves x 32 x 40 f16
    __shared__ __align__(16) char smem[70656];
    f16* kbuf = (f16*)smem;
    f16* vbuf = (f16*)(smem + 32768);
    f16* pb   = (f16*)(smem + 65536);
    int mode = g_mode[0];

    int bid = blockIdx.x;
    int gq = bid >> 3, x8 = bid & 7;
    int n = x8 >> 1;                 // batch -> XCD-pair affinity
    int itq = gq * 2 + (x8 & 1);
    int i0 = itq * 64;
    int tid = threadIdx.x, w = tid >> 6, lane = tid & 63;
    int quad = lane >> 4, l16 = lane & 15;

    const f16* Qb = g_q + n * CHW;
    const f16* Kb = g_k + n * CHW;
    const f16* Vb = g_v + n * CHW;
    float gam = mode ? ((const float*)gv)[0] : bf2f(((const ushort_t*)gv)[0]);
    gam = fin0(gam);

    // Q fragments: 2 i-tiles of 16 rows per wave (M=32)
    f16x8 qf[2][8];
#pragma unroll
    for (int mt = 0; mt < 2; mt++) {
        const f16* qrow = Qb + (i0 + w * 32 + mt * 16 + l16) * C_DIM;
#pragma unroll
        for (int kk = 0; kk < 8; kk++)
            qf[mt][kk] = *(const f16x8*)(qrow + kk * 32 + quad * 8);
    }

    f32x4 o_acc[2][16];
#pragma unroll
    for (int mt = 0; mt < 2; mt++)
#pragma unroll
        for (int i = 0; i < 16; i++) o_acc[mt][i] = f32x4{0.f, 0.f, 0.f, 0.f};
    float m_[2][4], l_[2][4];
#pragma unroll
    for (int mt = 0; mt < 2; mt++)
#pragma unroll
        for (int r = 0; r < 4; r++) { m_[mt][r] = -1e30f; l_[mt][r] = 0.f; }

    // async stage of K-tile (32j x 256c) and V-tile (256c x 32j) into LDS dbuf.
    // Swizzle lives in the per-lane GLOBAL address; LDS side is linear (HW: base+lane*16).
    auto stage = [&](int jt, int buf) {
#pragma unroll
        for (int s = 0; s < 8; ++s) {
            int idx = s * 128 + tid;
            int j = idx >> 5, gp = idx & 31;
            int gg = (gp & 24) | ((gp & 7) ^ (j & 7));
            gl2lds16(Kb + (jt * 32 + j) * C_DIM + gg * 8,
                     kbuf + (buf * 1024 + s * 128 + w * 64) * 8);
        }
#pragma unroll
        for (int s = 0; s < 8; ++s) {
            int idx = s * 128 + tid;
            int c = idx >> 2, jp = idx & 3;
            int jg = jp ^ (c & 3);
            gl2lds16(Vb + c * HW + jt * 32 + jg * 8,
                     vbuf + (buf * 1024 + s * 128 + w * 64) * 8);
        }
    };

    stage(0, 0);

    for (int jt = 0; jt < 128; ++jt) {
        int buf = jt & 1;
        __syncthreads();   // stage(jt) complete (vmcnt drain); prior reads of buf^1 done
        if (jt + 1 < 128) stage(jt + 1, buf ^ 1);

        const f16* kb = kbuf + buf * 1024 * 8;
        const f16* vb = vbuf + buf * 1024 * 8;

        // ---- S = Q K^T : 2 i-tiles x 2 j-tiles ----
        f32x4 s_[2][2];
        s_[0][0] = f32x4{0.f,0.f,0.f,0.f}; s_[0][1] = f32x4{0.f,0.f,0.f,0.f};
        s_[1][0] = f32x4{0.f,0.f,0.f,0.f}; s_[1][1] = f32x4{0.f,0.f,0.f,0.f};
#pragma unroll
        for (int kk = 0; kk < 8; kk++) {
            int cb = kk * 4 + quad;
            int pos = (cb & 24) | ((cb & 7) ^ (l16 & 7));   // j&7 == l16&7 for both j-tiles
            f16x8 kf0 = *(const f16x8*)(kb + (l16 * 32 + pos) * 8);
            f16x8 kf1 = *(const f16x8*)(kb + ((16 + l16) * 32 + pos) * 8);
            s_[0][0] = __builtin_amdgcn_mfma_f32_16x16x32_f16(qf[0][kk], kf0, s_[0][0], 0, 0, 0);
            s_[0][1] = __builtin_amdgcn_mfma_f32_16x16x32_f16(qf[0][kk], kf1, s_[0][1], 0, 0, 0);
            s_[1][0] = __builtin_amdgcn_mfma_f32_16x16x32_f16(qf[1][kk], kf0, s_[1][0], 0, 0, 0);
            s_[1][1] = __builtin_amdgcn_mfma_f32_16x16x32_f16(qf[1][kk], kf1, s_[1][1], 0, 0, 0);
        }

        // ---- online softmax; lane owns rows quad*4+r of each i-tile ----
        float al[2][4], p0[2][4], p1[2][4];
        float asum = 0.f;
#pragma unroll
        for (int mt = 0; mt < 2; mt++) {
            float mx[4];
#pragma unroll
            for (int r = 0; r < 4; r++) {
                float a = s_[mt][0][r], b = s_[mt][1][r];
                a = (a > -1e30f && a < 1e30f) ? a : -30000.f;
                b = (b > -1e30f && b < 1e30f) ? b : -30000.f;
                s_[mt][0][r] = a; s_[mt][1][r] = b;
                mx[r] = fmaxf(a, b);
            }
#pragma unroll
            for (int d = 1; d < 16; d <<= 1)
#pragma unroll
                for (int r = 0; r < 4; r++) mx[r] = fmaxf(mx[r], __shfl_xor(mx[r], d, 64));
            float rs[4];
#pragma unroll
            for (int r = 0; r < 4; r++) {
                float mn = fmaxf(m_[mt][r], mx[r]);
                al[mt][r] = __builtin_amdgcn_exp2f((m_[mt][r] - mn) * 1.4426950408889634f);
                p0[mt][r] = __builtin_amdgcn_exp2f((s_[mt][0][r] - mn) * 1.4426950408889634f);
                p1[mt][r] = __builtin_amdgcn_exp2f((s_[mt][1][r] - mn) * 1.4426950408889634f);
                rs[r] = p0[mt][r] + p1[mt][r];
                m_[mt][r] = mn;
            }
#pragma unroll
            for (int d = 1; d < 16; d <<= 1)
#pragma unroll
                for (int r = 0; r < 4; r++) rs[r] += __shfl_xor(rs[r], d, 64);
#pragma unroll
            for (int r = 0; r < 4; r++) {
                l_[mt][r] = l_[mt][r] * al[mt][r] + rs[r];
                asum += al[mt][r];
            }
        }
        if (__any(asum < 7.9999f)) {
#pragma unroll
            for (int mt = 0; mt < 2; mt++) {
                f32x4 av; av[0] = al[mt][0]; av[1] = al[mt][1]; av[2] = al[mt][2]; av[3] = al[mt][3];
#pragma unroll
                for (int t = 0; t < 16; t++) o_acc[mt][t] *= av;
            }
        }

        // ---- P: C-layout -> A-layout via per-wave LDS ----
        f16* pw = pb + w * 1280;
#pragma unroll
        for (int mt = 0; mt < 2; mt++)
#pragma unroll
            for (int r = 0; r < 4; r++) {
                pw[(mt * 16 + quad * 4 + r) * 40 + l16]      = (f16)p0[mt][r];
                pw[(mt * 16 + quad * 4 + r) * 40 + 16 + l16] = (f16)p1[mt][r];
            }
        asm volatile("" ::: "memory");
        f16x8 pf0 = *(const f16x8*)(pw + l16 * 40 + quad * 8);
        f16x8 pf1 = *(const f16x8*)(pw + (16 + l16) * 40 + quad * 8);

        // ---- O += P V ----
#pragma unroll
        for (int nt2 = 0; nt2 < 16; ++nt2) {
            int c = nt2 * 16 + l16;
            f16x8 vf = *(const f16x8*)(vb + (c * 4 + (quad ^ (c & 3))) * 8);
            o_acc[0][nt2] = __builtin_amdgcn_mfma_f32_16x16x32_f16(pf0, vf, o_acc[0][nt2], 0, 0, 0);
            o_acc[1][nt2] = __builtin_amdgcn_mfma_f32_16x16x32_f16(pf1, vf, o_acc[1][nt2], 0, 0, 0);
        }
    }

    // ---- epilogue: normalize, transpose via LDS (swizzled), residual, store ----
#pragma unroll
    for (int mt = 0; mt < 2; mt++) {
        f32x4 invl;
#pragma unroll
        for (int r = 0; r < 4; r++) invl[r] = (l_[mt][r] > 1e-30f) ? 1.0f / l_[mt][r] : 0.f;
#pragma unroll
        for (int t = 0; t < 16; t++) o_acc[mt][t] *= invl;
    }
    __syncthreads();   // all kbuf/vbuf/pb traffic done before reuse
    float* ob = (float*)smem;   // [c=256][irow=64], irow-base XOR-swizzled by (c&7)<<2
    int swz_w = (l16 & 7) << 2;
#pragma unroll
    for (int mt = 0; mt < 2; mt++)
#pragma unroll
        for (int nt2 = 0; nt2 < 16; nt2++) {
            int c = nt2 * 16 + l16;
            int rb = (w * 32 + mt * 16 + quad * 4) ^ swz_w;
            *(f32x4*)(ob + c * 64 + rb) = o_acc[mt][nt2];
        }
    __syncthreads();
    if (mode == 0) {
        const ushort_t* xb = (const ushort_t*)xv + n * CHW;
        ushort_t* outb = (ushort_t*)outv + n * CHW;
#pragma unroll
        for (int s = 0; s < 64; ++s) {
            int idx = s * 128 + tid;
            int c = idx >> 5, pr = idx & 31;
            int sz = (c & 7) << 2;
            float o0 = ob[c * 64 + ((pr * 2) ^ sz)];
            float o1 = ob[c * 64 + ((pr * 2 + 1) ^ sz)];
            u32 xp = *(const u32*)(xb + c * HW + i0 + pr * 2);
            float x0 = bf2f((ushort_t)(xp & 0xFFFF));
            float x1 = bf2f((ushort_t)(xp >> 16));
            u32 res = ((u32)f2bf(fin0(x1 + gam * o1)) << 16) | (u32)f2bf(fin0(x0 + gam * o0));
            *(u32*)(outb + c * HW + i0 + pr * 2) = res;
        }
    } else {
        const float* xb = (const float*)xv + n * CHW;
        float* outb = (float*)outv + n * CHW;
#pragma unroll
        for (int s = 0; s < 64; ++s) {
            int idx = s * 128 + tid;
            int c = idx >> 5, pr = idx & 31;
            int sz = (c & 7) << 2;
            float o0 = ob[c * 64 + ((pr * 2) ^ sz)];
            float o1 = ob[c * 64 + ((pr * 2 + 1) ^ sz)];
            float2 xp = *(const float2*)(xb + c * HW + i0 + pr * 2);
            float2 res;
            res.x = fin0(xp.x + gam * o0);
            res.y = fin0(xp.y + gam * o1);
            *(float2*)(outb + c * HW + i0 + pr * 2) = res;
        }
    }
}

extern "C" void kernel_launch(void* const* d_in, const int* in_sizes, int n_in,
                              void* d_out, int out_size, void* d_ws, size_t ws_size,
                              hipStream_t stream) {
    (void)d_ws; (void)ws_size;
    bool ok = (n_in == 8) &&
              in_sizes[0] == 4 * CHW &&
              in_sizes[1] == C_DIM * C_DIM && in_sizes[2] == C_DIM &&
              in_sizes[3] == C_DIM * C_DIM && in_sizes[4] == C_DIM &&
              in_sizes[5] == C_DIM * C_DIM && in_sizes[6] == C_DIM &&
              in_sizes[7] == 1 && out_size == 4 * CHW;
    if (!ok) {
        hipLaunchKernelGGL(k_sentinel, dim3((out_size + 255) / 256), dim3(256), 0, stream,
                           (ushort_t*)d_out, out_size);
        return;
    }
    hipLaunchKernelGGL(k_probe, dim3(1), dim3(64), 0, stream, d_in[0]);
    hipLaunchKernelGGL(k_transpose, dim3(64, 4, 4), dim3(256), 0, stream, d_in[0]);
    hipLaunchKernelGGL(k_proj, dim3(32, 6, 4), dim3(256), 0, stream,
                       d_in[1], d_in[2], d_in[3], d_in[4], d_in[5], d_in[6]);
    hipLaunchKernelGGL(k_attn, dim3(256), dim3(128), 0, stream, d_in[0], d_in[7], d_out);
}

// Round 7
// 312.580 us; speedup vs baseline: 1.9262x; 1.8547x over previous
//
#include <hip/hip_runtime.h>

typedef unsigned short ushort_t;
typedef unsigned int u32;
typedef _Float16 f16;
typedef f16 f16x8 __attribute__((ext_vector_type(8)));
typedef f16 f16x2 __attribute__((ext_vector_type(2)));
typedef ushort_t u16x8 __attribute__((ext_vector_type(8)));
typedef float f32x4 __attribute__((ext_vector_type(4)));

#define C_DIM 256
#define HW 4096
#define CHW (C_DIM*HW)
#define L2E 1.4426950408889634f

// Device-global scratch (no d_ws dependence). Internal pipeline is f16 always.
__device__ __align__(16) f16 g_xbT[4 * CHW];
__device__ __align__(16) f16 g_q[4 * CHW];
__device__ __align__(16) f16 g_k[4 * CHW];
__device__ __align__(16) f16 g_v[4 * CHW];
__device__ int g_mode[1];   // 0 = inputs bf16, 1 = inputs f32

__device__ __forceinline__ float bf2f(ushort_t h) {
    union { u32 u; float f; } v; v.u = ((u32)h) << 16; return v.f;
}
__device__ __forceinline__ ushort_t f2bf(float f) {
    union { float f; u32 u; } v; v.f = f;
    u32 r = v.u + 0x7FFF + ((v.u >> 16) & 1);
    return (ushort_t)(r >> 16);
}
__device__ __forceinline__ float fin0(float v) {
    return (v > -1e30f && v < 1e30f) ? v : 0.f;
}
__device__ __forceinline__ f16 sf16(float v) {
    return (f16)((v > -1e4f && v < 1e4f) ? v : 0.f);
}
__device__ __forceinline__ void gl2lds16(const f16* g, f16* l) {
    __builtin_amdgcn_global_load_lds(
        (const __attribute__((address_space(1))) u32*)g,
        (__attribute__((address_space(3))) u32*)l, 16, 0, 0);
}

// ---------------- kernel 0: dtype probe ----------------
__global__ void k_probe(const void* __restrict__ xv) {
    const ushort_t* xh = (const ushort_t*)xv;
    int lane = threadIdx.x;
    float s = 0.f;
    for (int i = lane; i < 2048; i += 64) {
        float v = fabsf(bf2f(xh[i]));
        v = (v < 1e6f) ? v : 1e6f;
        s += v;
    }
#pragma unroll
    for (int d = 1; d < 64; d <<= 1) s += __shfl_xor(s, d, 64);
    if (lane == 0) g_mode[0] = (s * (1.f / 2048.f) > 100.f) ? 1 : 0;
}

__global__ void k_sentinel(ushort_t* out, int n) {
    int i = blockIdx.x * 256 + threadIdx.x;
    if (i < n) out[i] = f2bf(777.f);
}

// ---------------- kernel 1: x (N,C,HW) -> g_xbT f16 (N,HW,C) ----------------
__global__ __launch_bounds__(256) void k_transpose(const void* __restrict__ xv) {
    __shared__ f16 t[64][66];
    int mode = g_mode[0];
    int n = blockIdx.z, c0 = blockIdx.y * 64, l0 = blockIdx.x * 64;
    int tid = threadIdx.x;
    f16* ob = g_xbT + n * CHW;
    int lq = (tid & 15) * 4;
    int cl = tid >> 4;
    if (mode == 0) {
        const ushort_t* xb = (const ushort_t*)xv + n * CHW;
#pragma unroll
        for (int p = 0; p < 4; ++p) {
            int c = cl + 16 * p;
            ushort4 v = *(const ushort4*)(xb + (c0 + c) * HW + l0 + lq);
            t[lq + 0][c] = sf16(bf2f(v.x));
            t[lq + 1][c] = sf16(bf2f(v.y));
            t[lq + 2][c] = sf16(bf2f(v.z));
            t[lq + 3][c] = sf16(bf2f(v.w));
        }
    } else {
        const float* xb = (const float*)xv + n * CHW;
#pragma unroll
        for (int p = 0; p < 4; ++p) {
            int c = cl + 16 * p;
            float4 v = *(const float4*)(xb + (c0 + c) * HW + l0 + lq);
            t[lq + 0][c] = sf16(v.x);
            t[lq + 1][c] = sf16(v.y);
            t[lq + 2][c] = sf16(v.z);
            t[lq + 3][c] = sf16(v.w);
        }
    }
    __syncthreads();
    int c2 = (tid & 31) * 2;
    int lr = tid >> 5;
#pragma unroll
    for (int p = 0; p < 8; ++p) {
        int l = lr + 8 * p;
        u32 pair = *(const u32*)&t[l][c2];
        *(u32*)(ob + (l0 + l) * C_DIM + c0 + c2) = pair;
    }
}

// ---------------- kernel 2: projections (f16 MFMA) ----------------
__global__ __launch_bounds__(256) void k_proj(
    const void* __restrict__ Wq, const void* __restrict__ bq,
    const void* __restrict__ Wk, const void* __restrict__ bk,
    const void* __restrict__ Wv, const void* __restrict__ bv)
{
    __shared__ __align__(16) f16 lds_x[128 * 64];
    __shared__ __align__(16) f16 lds_w[128 * 64];
    int mode = g_mode[0];
    int l0 = blockIdx.x * 128;
    int og0 = blockIdx.y * 128;
    int n = blockIdx.z;
    int mat = og0 >> 8;       // 0=q,1=k,2=v
    int om0 = og0 & 255;
    const void* W = (mat == 0) ? Wq : (mat == 1) ? Wk : Wv;
    const void* bias = (mat == 0) ? bq : (mat == 1) ? bk : bv;
    int tid = threadIdx.x, w = tid >> 6, lane = tid & 63;
    int quad = lane >> 4, l16 = lane & 15;
    const f16* xb = g_xbT + n * CHW;

    f32x4 acc[2][8];
#pragma unroll
    for (int a = 0; a < 2; a++)
#pragma unroll
        for (int b = 0; b < 8; b++) acc[a][b] = f32x4{0.f, 0.f, 0.f, 0.f};

    for (int ch = 0; ch < 4; ++ch) {
        int cc0 = ch * 64;
        f16x8 xs[4], wsr[4];
#pragma unroll
        for (int ti = 0; ti < 4; ++ti) {
            int s = (w * 4 + ti) * 64 + lane;
            int row = s >> 3, gp = s & 7;
            xs[ti] = *(const f16x8*)(xb + (l0 + row) * C_DIM + cc0 + gp * 8);
            f16x8 h;
            if (mode == 0) {
                u16x8 wv = *(const u16x8*)((const ushort_t*)W + (om0 + row) * C_DIM + cc0 + gp * 8);
#pragma unroll
                for (int e = 0; e < 8; e++) h[e] = sf16(bf2f(wv[e]));
            } else {
                const float* wf = (const float*)W + (om0 + row) * C_DIM + cc0 + gp * 8;
#pragma unroll
                for (int e = 0; e < 8; e++) h[e] = sf16(wf[e]);
            }
            wsr[ti] = h;
        }
        __syncthreads();
#pragma unroll
        for (int ti = 0; ti < 4; ++ti) {
            int s = (w * 4 + ti) * 64 + lane;
            int row = s >> 3, gp = s & 7;
            int pos = gp ^ (row & 7);
            *(f16x8*)(lds_x + (row * 8 + pos) * 8) = xs[ti];
            *(f16x8*)(lds_w + (row * 8 + pos) * 8) = wsr[ti];
        }
        __syncthreads();
#pragma unroll
        for (int ks = 0; ks < 2; ++ks) {
            f16x8 af[2];
#pragma unroll
            for (int mt = 0; mt < 2; ++mt) {
                int row = w * 32 + mt * 16 + l16;
                int g = ks * 4 + quad;
                int pos = g ^ (row & 7);
                af[mt] = *(const f16x8*)(lds_x + (row * 8 + pos) * 8);
            }
#pragma unroll
            for (int nt = 0; nt < 8; ++nt) {
                int rowo = nt * 16 + l16;
                int g = ks * 4 + quad;
                int pos = g ^ (rowo & 7);
                f16x8 bfv = *(const f16x8*)(lds_w + (rowo * 8 + pos) * 8);
                if (mat < 2) {
                    acc[0][nt] = __builtin_amdgcn_mfma_f32_16x16x32_f16(af[0], bfv, acc[0][nt], 0, 0, 0);
                    acc[1][nt] = __builtin_amdgcn_mfma_f32_16x16x32_f16(af[1], bfv, acc[1][nt], 0, 0, 0);
                } else {
                    acc[0][nt] = __builtin_amdgcn_mfma_f32_16x16x32_f16(bfv, af[0], acc[0][nt], 0, 0, 0);
                    acc[1][nt] = __builtin_amdgcn_mfma_f32_16x16x32_f16(bfv, af[1], acc[1][nt], 0, 0, 0);
                }
            }
        }
        __syncthreads();
    }

    auto loadb = [&](int i) -> float {
        return mode ? ((const float*)bias)[i] : bf2f(((const ushort_t*)bias)[i]);
    };
    if (mat < 2) {
        f16* T = ((mat == 0) ? g_q : g_k) + n * CHW;
        float bvv[8];
#pragma unroll
        for (int nt = 0; nt < 8; nt++) bvv[nt] = loadb(om0 + nt * 16 + l16);
#pragma unroll
        for (int mt = 0; mt < 2; mt++)
#pragma unroll
            for (int nt = 0; nt < 8; nt++)
#pragma unroll
                for (int r = 0; r < 4; r++) {
                    int l = l0 + w * 32 + mt * 16 + quad * 4 + r;
                    int o = om0 + nt * 16 + l16;
                    T[l * C_DIM + o] = sf16(acc[mt][nt][r] + bvv[nt]);
                }
    } else {
        f16* T = g_v + n * CHW;
#pragma unroll
        for (int mt = 0; mt < 2; mt++)
#pragma unroll
            for (int nt = 0; nt < 8; nt++)
#pragma unroll
                for (int r = 0; r < 4; r++) {
                    int o = om0 + nt * 16 + quad * 4 + r;
                    int l = l0 + w * 32 + mt * 16 + l16;
                    T[o * HW + l] = sf16(acc[mt][nt][r] + loadb(o));
                }
    }
}

// ---------------- kernel 3: flash attention, S^T orientation ----------------
// 256 blocks x 256 thr (4 waves). BM=64 (M=16/wave), BN=32 j per iter.
// S^T = K·Q^T via mfma(kf, qf): D[row=j][col=i] -> softmax per-lane (i=l16),
// m/l/alpha are per-lane scalars; O^T[c][i] += V·P^T; direct (c,i) epilogue.
__global__ __launch_bounds__(256, 1) void k_attn(
    const void* __restrict__ xv,
    const void* __restrict__ gv, void* __restrict__ outv)
{
    __shared__ __align__(16) char smem[70656];
    f16* kbuf = (f16*)smem;             // 2 x 8192 f16 (32 j x 32 granules, swizzled)
    f16* vbuf = (f16*)(smem + 32768);   // 2 x 8192 f16 (256 c x 4 granules, swizzled)
    f16* pb   = (f16*)(smem + 65536);   // 4 waves x 16 i x 40 f16 (P^T, [i][j])
    int mode = g_mode[0];

    int bid = blockIdx.x;
    int gq = bid >> 3, x8 = bid & 7;
    int n = x8 >> 1;                 // batch -> XCD-pair affinity
    int itq = gq * 2 + (x8 & 1);
    int i0 = itq * 64;
    int tid = threadIdx.x, w = tid >> 6, lane = tid & 63;
    int quad = lane >> 4, l16 = lane & 15;

    const f16* Qb = g_q + n * CHW;
    const f16* Kb = g_k + n * CHW;
    const f16* Vb = g_v + n * CHW;
    float gam = mode ? ((const float*)gv)[0] : bf2f(((const ushort_t*)gv)[0]);
    gam = fin0(gam);
    f16* pw = pb + w * 640;

    // Q fragments (B-operand): lane l16 -> i, 8 contiguous c per kk/quad
    f16x8 qf[8];
    {
        const f16* qrow = Qb + (i0 + w * 16 + l16) * C_DIM + quad * 8;
#pragma unroll
        for (int kk = 0; kk < 8; kk++)
            qf[kk] = *(const f16x8*)(qrow + kk * 32);
    }

    f32x4 o_acc[16];
#pragma unroll
    for (int i = 0; i < 16; i++) o_acc[i] = f32x4{0.f, 0.f, 0.f, 0.f};
    float m_ = -1e30f, l_ = 0.f;

    // stage K-tile (32j x 256c) + V-tile (256c x 32j) into LDS dbuf.
    // Swizzle encoded in per-lane GLOBAL address; LDS dest is linear (base+lane*16).
    auto stage = [&](int jt, int buf) {
#pragma unroll
        for (int s = 0; s < 4; ++s) {
            int idx = s * 256 + tid;
            int j = idx >> 5, gp = idx & 31;
            int gg = (gp & 24) | ((gp & 7) ^ (j & 7));
            gl2lds16(Kb + (jt * 32 + j) * C_DIM + gg * 8,
                     kbuf + (buf * 1024 + s * 256 + w * 64) * 8);
        }
#pragma unroll
        for (int s = 0; s < 4; ++s) {
            int idx = s * 256 + tid;
            int c = idx >> 2, jp = idx & 3;
            int jg = jp ^ ((c >> 1) & 3);   // bank-spread: 2-way max (free)
            gl2lds16(Vb + c * HW + jt * 32 + jg * 8,
                     vbuf + (buf * 1024 + s * 256 + w * 64) * 8);
        }
    };

    stage(0, 0);

    for (int jt = 0; jt < 128; ++jt) {
        int buf = jt & 1;
        __syncthreads();   // stage(jt) complete (vmcnt drain)
        if (jt + 1 < 128) stage(jt + 1, buf ^ 1);

        const f16* kb = kbuf + buf * 8192;
        const f16* vb = vbuf + buf * 8192;

        // ---- S^T = K Q^T : D[j=quad*4+r][i=l16], 2 j-tiles ----
        f32x4 st0 = {0.f, 0.f, 0.f, 0.f}, st1 = {0.f, 0.f, 0.f, 0.f};
#pragma unroll
        for (int kk = 0; kk < 8; kk++) {
            int g = kk * 4 + quad;
            int pos = (g & 24) | ((g & 7) ^ (l16 & 7));
            f16x8 kf0 = *(const f16x8*)(kb + (l16 * 32 + pos) * 8);
            f16x8 kf1 = *(const f16x8*)(kb + ((16 + l16) * 32 + pos) * 8);
            st0 = __builtin_amdgcn_mfma_f32_16x16x32_f16(kf0, qf[kk], st0, 0, 0, 0);
            st1 = __builtin_amdgcn_mfma_f32_16x16x32_f16(kf1, qf[kk], st1, 0, 0, 0);
        }

        // ---- per-lane online softmax over j (column i = l16) ----
        float smax = fmaxf(fmaxf(fmaxf(st0[0], st0[1]), fmaxf(st0[2], st0[3])),
                           fmaxf(fmaxf(st1[0], st1[1]), fmaxf(st1[2], st1[3])));
        smax = fmaxf(smax, __shfl_xor(smax, 16, 64));
        smax = fmaxf(smax, __shfl_xor(smax, 32, 64));
        float mn = fmaxf(m_, smax);
        float al = __builtin_amdgcn_exp2f((m_ - mn) * L2E);
        float p0[4], p1[4], rs = 0.f;
#pragma unroll
        for (int r = 0; r < 4; r++) {
            p0[r] = __builtin_amdgcn_exp2f((st0[r] - mn) * L2E);
            p1[r] = __builtin_amdgcn_exp2f((st1[r] - mn) * L2E);
            rs += p0[r] + p1[r];
        }
        m_ = mn;
        rs += __shfl_xor(rs, 16, 64);
        rs += __shfl_xor(rs, 32, 64);
        l_ = l_ * al + rs;
        if (__any(al < 1.0f)) {
#pragma unroll
            for (int t = 0; t < 16; t++) o_acc[t] *= al;
        }

        // ---- P^T to LDS [i][j] (packed f16x2 writes), read back as B-frag ----
        *(f16x2*)(pw + l16 * 40 + quad * 4)          = f16x2{(f16)p0[0], (f16)p0[1]};
        *(f16x2*)(pw + l16 * 40 + quad * 4 + 2)      = f16x2{(f16)p0[2], (f16)p0[3]};
        *(f16x2*)(pw + l16 * 40 + 16 + quad * 4)     = f16x2{(f16)p1[0], (f16)p1[1]};
        *(f16x2*)(pw + l16 * 40 + 16 + quad * 4 + 2) = f16x2{(f16)p1[2], (f16)p1[3]};
        asm volatile("" ::: "memory");   // per-wave DS in-order; block compiler reorder
        f16x8 pfrag = *(const f16x8*)(pw + l16 * 40 + quad * 8);

        // ---- O^T += V P^T : D[c=quad*4+r][i=l16], 16 c-tiles ----
#pragma unroll
        for (int ct = 0; ct < 16; ++ct) {
            int c = ct * 16 + l16;
            int pos = quad ^ ((c >> 1) & 3);
            f16x8 vf = *(const f16x8*)(vb + (c * 4 + pos) * 8);
            o_acc[ct] = __builtin_amdgcn_mfma_f32_16x16x32_f16(vf, pfrag, o_acc[ct], 0, 0, 0);
        }
    }

    // ---- epilogue: normalize (per-lane scalar), residual, direct (c,i) store ----
    float invl = (l_ > 1e-30f) ? 1.0f / l_ : 0.f;
#pragma unroll
    for (int t = 0; t < 16; t++) o_acc[t] *= invl;
    int ig = i0 + w * 16 + l16;
    if (mode == 0) {
        const ushort_t* xb = (const ushort_t*)xv + n * CHW;
        ushort_t* outb = (ushort_t*)outv + n * CHW;
#pragma unroll
        for (int ct = 0; ct < 16; ++ct)
#pragma unroll
            for (int r = 0; r < 4; r++) {
                int c = ct * 16 + quad * 4 + r;
                float xvv = bf2f(xb[c * HW + ig]);
                outb[c * HW + ig] = f2bf(fin0(xvv + gam * o_acc[ct][r]));
            }
    } else {
        const float* xb = (const float*)xv + n * CHW;
        float* outb = (float*)outv + n * CHW;
#pragma unroll
        for (int ct = 0; ct < 16; ++ct)
#pragma unroll
            for (int r = 0; r < 4; r++) {
                int c = ct * 16 + quad * 4 + r;
                outb[c * HW + ig] = fin0(xb[c * HW + ig] + gam * o_acc[ct][r]);
            }
    }
}

extern "C" void kernel_launch(void* const* d_in, const int* in_sizes, int n_in,
                              void* d_out, int out_size, void* d_ws, size_t ws_size,
                              hipStream_t stream) {
    (void)d_ws; (void)ws_size;
    bool ok = (n_in == 8) &&
              in_sizes[0] == 4 * CHW &&
              in_sizes[1] == C_DIM * C_DIM && in_sizes[2] == C_DIM &&
              in_sizes[3] == C_DIM * C_DIM && in_sizes[4] == C_DIM &&
              in_sizes[5] == C_DIM * C_DIM && in_sizes[6] == C_DIM &&
              in_sizes[7] == 1 && out_size == 4 * CHW;
    if (!ok) {
        hipLaunchKernelGGL(k_sentinel, dim3((out_size + 255) / 256), dim3(256), 0, stream,
                           (ushort_t*)d_out, out_size);
        return;
    }
    hipLaunchKernelGGL(k_probe, dim3(1), dim3(64), 0, stream, d_in[0]);
    hipLaunchKernelGGL(k_transpose, dim3(64, 4, 4), dim3(256), 0, stream, d_in[0]);
    hipLaunchKernelGGL(k_proj, dim3(32, 6, 4), dim3(256), 0, stream,
                       d_in[1], d_in[2], d_in[3], d_in[4], d_in[5], d_in[6]);
    hipLaunchKernelGGL(k_attn, dim3(256), dim3(256), 0, stream, d_in[0], d_in[7], d_out);
}

// Round 8
// 304.544 us; speedup vs baseline: 1.9770x; 1.0264x over previous
//
#include <hip/hip_runtime.h>

typedef unsigned short ushort_t;
typedef unsigned int u32;
typedef _Float16 f16;
typedef f16 f16x8 __attribute__((ext_vector_type(8)));
typedef f16 f16x2 __attribute__((ext_vector_type(2)));
typedef ushort_t u16x8 __attribute__((ext_vector_type(8)));
typedef float f32x4 __attribute__((ext_vector_type(4)));

#define C_DIM 256
#define HW 4096
#define CHW (C_DIM*HW)
#define L2E 1.4426950408889634f

// Device-global scratch (no d_ws dependence). Internal pipeline is f16.
__device__ __align__(16) f16 g_xbT[4 * CHW];
__device__ __align__(16) f16 g_q[4 * CHW];
__device__ __align__(16) f16 g_k[4 * CHW];
__device__ __align__(16) f16 g_v[4 * CHW];
__device__ __align__(16) float g_opart[2 * 4 * CHW];  // [jh][n][c][i] unnormalized O^T
__device__ float g_ml[2 * 4 * 2 * HW];                // [jh][n][{m,l}][i]
__device__ int g_mode[1];   // 0 = inputs bf16, 1 = inputs f32

__device__ __forceinline__ float bf2f(ushort_t h) {
    union { u32 u; float f; } v; v.u = ((u32)h) << 16; return v.f;
}
__device__ __forceinline__ ushort_t f2bf(float f) {
    union { float f; u32 u; } v; v.f = f;
    u32 r = v.u + 0x7FFF + ((v.u >> 16) & 1);
    return (ushort_t)(r >> 16);
}
__device__ __forceinline__ float fin0(float v) {
    return (v > -1e30f && v < 1e30f) ? v : 0.f;
}
__device__ __forceinline__ f16 sf16(float v) {
    return (f16)((v > -1e4f && v < 1e4f) ? v : 0.f);
}
__device__ __forceinline__ void gl2lds16(const f16* g, f16* l) {
    __builtin_amdgcn_global_load_lds(
        (const __attribute__((address_space(1))) u32*)g,
        (__attribute__((address_space(3))) u32*)l, 16, 0, 0);
}

// ---------------- kernel 0: dtype probe ----------------
__global__ void k_probe(const void* __restrict__ xv) {
    const ushort_t* xh = (const ushort_t*)xv;
    int lane = threadIdx.x;
    float s = 0.f;
    for (int i = lane; i < 2048; i += 64) {
        float v = fabsf(bf2f(xh[i]));
        v = (v < 1e6f) ? v : 1e6f;
        s += v;
    }
#pragma unroll
    for (int d = 1; d < 64; d <<= 1) s += __shfl_xor(s, d, 64);
    if (lane == 0) g_mode[0] = (s * (1.f / 2048.f) > 100.f) ? 1 : 0;
}

__global__ void k_sentinel(ushort_t* out, int n) {
    int i = blockIdx.x * 256 + threadIdx.x;
    if (i < n) out[i] = f2bf(777.f);
}

// ---------------- kernel 1: x (N,C,HW) -> g_xbT f16 (N,HW,C) ----------------
__global__ __launch_bounds__(256) void k_transpose(const void* __restrict__ xv) {
    __shared__ f16 t[64][66];
    int mode = g_mode[0];
    int n = blockIdx.z, c0 = blockIdx.y * 64, l0 = blockIdx.x * 64;
    int tid = threadIdx.x;
    f16* ob = g_xbT + n * CHW;
    int lq = (tid & 15) * 4;
    int cl = tid >> 4;
    if (mode == 0) {
        const ushort_t* xb = (const ushort_t*)xv + n * CHW;
#pragma unroll
        for (int p = 0; p < 4; ++p) {
            int c = cl + 16 * p;
            ushort4 v = *(const ushort4*)(xb + (c0 + c) * HW + l0 + lq);
            t[lq + 0][c] = sf16(bf2f(v.x));
            t[lq + 1][c] = sf16(bf2f(v.y));
            t[lq + 2][c] = sf16(bf2f(v.z));
            t[lq + 3][c] = sf16(bf2f(v.w));
        }
    } else {
        const float* xb = (const float*)xv + n * CHW;
#pragma unroll
        for (int p = 0; p < 4; ++p) {
            int c = cl + 16 * p;
            float4 v = *(const float4*)(xb + (c0 + c) * HW + l0 + lq);
            t[lq + 0][c] = sf16(v.x);
            t[lq + 1][c] = sf16(v.y);
            t[lq + 2][c] = sf16(v.z);
            t[lq + 3][c] = sf16(v.w);
        }
    }
    __syncthreads();
    int c2 = (tid & 31) * 2;
    int lr = tid >> 5;
#pragma unroll
    for (int p = 0; p < 8; ++p) {
        int l = lr + 8 * p;
        u32 pair = *(const u32*)&t[l][c2];
        *(u32*)(ob + (l0 + l) * C_DIM + c0 + c2) = pair;
    }
}

// ---------------- kernel 2: projections (f16 MFMA) ----------------
__global__ __launch_bounds__(256) void k_proj(
    const void* __restrict__ Wq, const void* __restrict__ bq,
    const void* __restrict__ Wk, const void* __restrict__ bk,
    const void* __restrict__ Wv, const void* __restrict__ bv)
{
    __shared__ __align__(16) f16 lds_x[128 * 64];
    __shared__ __align__(16) f16 lds_w[128 * 64];
    int mode = g_mode[0];
    int l0 = blockIdx.x * 128;
    int og0 = blockIdx.y * 128;
    int n = blockIdx.z;
    int mat = og0 >> 8;       // 0=q,1=k,2=v
    int om0 = og0 & 255;
    const void* W = (mat == 0) ? Wq : (mat == 1) ? Wk : Wv;
    const void* bias = (mat == 0) ? bq : (mat == 1) ? bk : bv;
    int tid = threadIdx.x, w = tid >> 6, lane = tid & 63;
    int quad = lane >> 4, l16 = lane & 15;
    const f16* xb = g_xbT + n * CHW;

    f32x4 acc[2][8];
#pragma unroll
    for (int a = 0; a < 2; a++)
#pragma unroll
        for (int b = 0; b < 8; b++) acc[a][b] = f32x4{0.f, 0.f, 0.f, 0.f};

    for (int ch = 0; ch < 4; ++ch) {
        int cc0 = ch * 64;
        f16x8 xs[4], wsr[4];
#pragma unroll
        for (int ti = 0; ti < 4; ++ti) {
            int s = (w * 4 + ti) * 64 + lane;
            int row = s >> 3, gp = s & 7;
            xs[ti] = *(const f16x8*)(xb + (l0 + row) * C_DIM + cc0 + gp * 8);
            f16x8 h;
            if (mode == 0) {
                u16x8 wv = *(const u16x8*)((const ushort_t*)W + (om0 + row) * C_DIM + cc0 + gp * 8);
#pragma unroll
                for (int e = 0; e < 8; e++) h[e] = sf16(bf2f(wv[e]));
            } else {
                const float* wf = (const float*)W + (om0 + row) * C_DIM + cc0 + gp * 8;
#pragma unroll
                for (int e = 0; e < 8; e++) h[e] = sf16(wf[e]);
            }
            wsr[ti] = h;
        }
        __syncthreads();
#pragma unroll
        for (int ti = 0; ti < 4; ++ti) {
            int s = (w * 4 + ti) * 64 + lane;
            int row = s >> 3, gp = s & 7;
            int pos = gp ^ (row & 7);
            *(f16x8*)(lds_x + (row * 8 + pos) * 8) = xs[ti];
            *(f16x8*)(lds_w + (row * 8 + pos) * 8) = wsr[ti];
        }
        __syncthreads();
#pragma unroll
        for (int ks = 0; ks < 2; ++ks) {
            f16x8 af[2];
#pragma unroll
            for (int mt = 0; mt < 2; ++mt) {
                int row = w * 32 + mt * 16 + l16;
                int g = ks * 4 + quad;
                int pos = g ^ (row & 7);
                af[mt] = *(const f16x8*)(lds_x + (row * 8 + pos) * 8);
            }
#pragma unroll
            for (int nt = 0; nt < 8; ++nt) {
                int rowo = nt * 16 + l16;
                int g = ks * 4 + quad;
                int pos = g ^ (rowo & 7);
                f16x8 bfv = *(const f16x8*)(lds_w + (rowo * 8 + pos) * 8);
                if (mat < 2) {
                    acc[0][nt] = __builtin_amdgcn_mfma_f32_16x16x32_f16(af[0], bfv, acc[0][nt], 0, 0, 0);
                    acc[1][nt] = __builtin_amdgcn_mfma_f32_16x16x32_f16(af[1], bfv, acc[1][nt], 0, 0, 0);
                } else {
                    acc[0][nt] = __builtin_amdgcn_mfma_f32_16x16x32_f16(bfv, af[0], acc[0][nt], 0, 0, 0);
                    acc[1][nt] = __builtin_amdgcn_mfma_f32_16x16x32_f16(bfv, af[1], acc[1][nt], 0, 0, 0);
                }
            }
        }
        __syncthreads();
    }

    auto loadb = [&](int i) -> float {
        return mode ? ((const float*)bias)[i] : bf2f(((const ushort_t*)bias)[i]);
    };
    if (mat < 2) {
        f16* T = ((mat == 0) ? g_q : g_k) + n * CHW;
        float bvv[8];
#pragma unroll
        for (int nt = 0; nt < 8; nt++) bvv[nt] = loadb(om0 + nt * 16 + l16);
#pragma unroll
        for (int mt = 0; mt < 2; mt++)
#pragma unroll
            for (int nt = 0; nt < 8; nt++)
#pragma unroll
                for (int r = 0; r < 4; r++) {
                    int l = l0 + w * 32 + mt * 16 + quad * 4 + r;
                    int o = om0 + nt * 16 + l16;
                    T[l * C_DIM + o] = sf16(acc[mt][nt][r] + bvv[nt]);
                }
    } else {
        f16* T = g_v + n * CHW;
#pragma unroll
        for (int mt = 0; mt < 2; mt++)
#pragma unroll
            for (int nt = 0; nt < 8; nt++)
#pragma unroll
                for (int r = 0; r < 4; r++) {
                    int o = om0 + nt * 16 + quad * 4 + r;
                    int l = l0 + w * 32 + mt * 16 + l16;
                    T[o * HW + l] = sf16(acc[mt][nt][r] + loadb(o));
                }
    }
}

// ---------------- kernel 3: flash attention, S^T, M=32/wave, split-j ----------------
// 512 blocks x 128 thr (2 waves). Block = (n, i-tile of 64, j-half).
// Wave covers i=32 (2 mt groups of 16). Each kf/vf LDS read feeds 2 MFMAs.
// Emits unnormalized O^T partial + (m,l) per i; k_combine merges halves.
__global__ __launch_bounds__(128, 1) void k_attn() {
    __shared__ __align__(16) char smem[70656];
    f16* kbuf = (f16*)smem;             // 2 x 8192 f16 (32 j x 32 granules, swizzled)
    f16* vbuf = (f16*)(smem + 32768);   // 2 x 8192 f16 (256 c x 4 granules, swizzled)
    f16* pb   = (f16*)(smem + 65536);   // 2 waves x 2 mt x 16 i x 40 f16

    int bid = blockIdx.x;
    int x8 = bid & 7;
    int n = x8 >> 1, jh = x8 & 1;       // batch + j-half -> XCD affinity
    int i0 = (bid >> 3) * 64;           // 64 i-tiles of BM=64
    int tid = threadIdx.x, w = tid >> 6, lane = tid & 63;
    int quad = lane >> 4, l16 = lane & 15;

    const f16* Qb = g_q + n * CHW;
    const f16* Kb = g_k + n * CHW;
    const f16* Vb = g_v + n * CHW;
    f16* pw = pb + w * 1280;

    // Precomputed LDS read offsets (f16-element units)
    int koff0[8], koff1[8], voff[16];
#pragma unroll
    for (int kk = 0; kk < 8; kk++) {
        int g2 = kk * 4 + quad;
        int pos = (g2 & 24) | ((g2 & 7) ^ (l16 & 7));
        koff0[kk] = (l16 * 32 + pos) * 8;
        koff1[kk] = ((16 + l16) * 32 + pos) * 8;
    }
#pragma unroll
    for (int ct = 0; ct < 16; ct++) {
        int c = ct * 16 + l16;
        voff[ct] = (c * 4 + (quad ^ ((c >> 1) & 3))) * 8;
    }

    // Q fragments (B-operand), 2 i-groups of 16
    f16x8 qf[2][8];
#pragma unroll
    for (int mt = 0; mt < 2; mt++) {
        const f16* qrow = Qb + (i0 + w * 32 + mt * 16 + l16) * C_DIM + quad * 8;
#pragma unroll
        for (int kk = 0; kk < 8; kk++)
            qf[mt][kk] = *(const f16x8*)(qrow + kk * 32);
    }

    f32x4 o_acc[2][16];
#pragma unroll
    for (int mt = 0; mt < 2; mt++)
#pragma unroll
        for (int i = 0; i < 16; i++) o_acc[mt][i] = f32x4{0.f, 0.f, 0.f, 0.f};
    float m_[2] = {-1e30f, -1e30f}, l_[2] = {0.f, 0.f};

    auto stage = [&](int jt, int buf) {
#pragma unroll
        for (int s = 0; s < 8; ++s) {
            int idx = s * 128 + tid;
            int j = idx >> 5, gp = idx & 31;
            int gg = (gp & 24) | ((gp & 7) ^ (j & 7));
            gl2lds16(Kb + (jt * 32 + j) * C_DIM + gg * 8,
                     kbuf + (buf * 1024 + s * 128 + w * 64) * 8);
        }
#pragma unroll
        for (int s = 0; s < 8; ++s) {
            int idx = s * 128 + tid;
            int c = idx >> 2, jp = idx & 3;
            int jg = jp ^ ((c >> 1) & 3);
            gl2lds16(Vb + c * HW + jt * 32 + jg * 8,
                     vbuf + (buf * 1024 + s * 128 + w * 64) * 8);
        }
    };

    int jt0 = jh * 64;
    stage(jt0, 0);

    for (int it = 0; it < 64; ++it) {
        int buf = it & 1;
        __syncthreads();
        if (it + 1 < 64) stage(jt0 + it + 1, buf ^ 1);

        const f16* kb = kbuf + buf * 8192;
        const f16* vb = vbuf + buf * 8192;

        // ---- S^T = K Q^T : st[mt][jtile], D[j=jtile*16+quad*4+r][i=l16] ----
        f32x4 st[2][2];
        st[0][0] = f32x4{0.f,0.f,0.f,0.f}; st[0][1] = f32x4{0.f,0.f,0.f,0.f};
        st[1][0] = f32x4{0.f,0.f,0.f,0.f}; st[1][1] = f32x4{0.f,0.f,0.f,0.f};
#pragma unroll
        for (int kk = 0; kk < 8; kk++) {
            f16x8 kf0 = *(const f16x8*)(kb + koff0[kk]);
            f16x8 kf1 = *(const f16x8*)(kb + koff1[kk]);
            st[0][0] = __builtin_amdgcn_mfma_f32_16x16x32_f16(kf0, qf[0][kk], st[0][0], 0, 0, 0);
            st[0][1] = __builtin_amdgcn_mfma_f32_16x16x32_f16(kf1, qf[0][kk], st[0][1], 0, 0, 0);
            st[1][0] = __builtin_amdgcn_mfma_f32_16x16x32_f16(kf0, qf[1][kk], st[1][0], 0, 0, 0);
            st[1][1] = __builtin_amdgcn_mfma_f32_16x16x32_f16(kf1, qf[1][kk], st[1][1], 0, 0, 0);
        }

        // ---- per-lane online softmax (column i = l16 of group mt) ----
        float al[2];
        float pv0[2][4], pv1[2][4];
#pragma unroll
        for (int mt = 0; mt < 2; mt++) {
#pragma unroll
            for (int r = 0; r < 4; r++) {
                float a = st[mt][0][r], b = st[mt][1][r];
                st[mt][0][r] = (a > -1e30f && a < 1e30f) ? a : -30000.f;
                st[mt][1][r] = (b > -1e30f && b < 1e30f) ? b : -30000.f;
            }
            float smax = fmaxf(fmaxf(fmaxf(st[mt][0][0], st[mt][0][1]), fmaxf(st[mt][0][2], st[mt][0][3])),
                               fmaxf(fmaxf(st[mt][1][0], st[mt][1][1]), fmaxf(st[mt][1][2], st[mt][1][3])));
            smax = fmaxf(smax, __shfl_xor(smax, 16, 64));
            smax = fmaxf(smax, __shfl_xor(smax, 32, 64));
            float mn = fmaxf(m_[mt], smax);
            al[mt] = __builtin_amdgcn_exp2f((m_[mt] - mn) * L2E);
            float rs = 0.f;
#pragma unroll
            for (int r = 0; r < 4; r++) {
                pv0[mt][r] = __builtin_amdgcn_exp2f((st[mt][0][r] - mn) * L2E);
                pv1[mt][r] = __builtin_amdgcn_exp2f((st[mt][1][r] - mn) * L2E);
                rs += pv0[mt][r] + pv1[mt][r];
            }
            m_[mt] = mn;
            rs += __shfl_xor(rs, 16, 64);
            rs += __shfl_xor(rs, 32, 64);
            l_[mt] = l_[mt] * al[mt] + rs;
        }
        if (__any((al[0] < 1.0f) || (al[1] < 1.0f))) {
#pragma unroll
            for (int mt = 0; mt < 2; mt++)
#pragma unroll
                for (int t = 0; t < 16; t++) o_acc[mt][t] *= al[mt];
        }

        // ---- P^T to LDS [i][j], read back as B-frag ----
#pragma unroll
        for (int mt = 0; mt < 2; mt++) {
            f16* pm = pw + mt * 640 + l16 * 40;
            *(f16x2*)(pm + quad * 4)          = f16x2{(f16)pv0[mt][0], (f16)pv0[mt][1]};
            *(f16x2*)(pm + quad * 4 + 2)      = f16x2{(f16)pv0[mt][2], (f16)pv0[mt][3]};
            *(f16x2*)(pm + 16 + quad * 4)     = f16x2{(f16)pv1[mt][0], (f16)pv1[mt][1]};
            *(f16x2*)(pm + 16 + quad * 4 + 2) = f16x2{(f16)pv1[mt][2], (f16)pv1[mt][3]};
        }
        asm volatile("" ::: "memory");
        f16x8 pf0 = *(const f16x8*)(pw + l16 * 40 + quad * 8);
        f16x8 pf1 = *(const f16x8*)(pw + 640 + l16 * 40 + quad * 8);

        // ---- O^T += V P^T : each vf feeds both i-groups ----
#pragma unroll
        for (int ct = 0; ct < 16; ++ct) {
            f16x8 vf = *(const f16x8*)(vb + voff[ct]);
            o_acc[0][ct] = __builtin_amdgcn_mfma_f32_16x16x32_f16(vf, pf0, o_acc[0][ct], 0, 0, 0);
            o_acc[1][ct] = __builtin_amdgcn_mfma_f32_16x16x32_f16(vf, pf1, o_acc[1][ct], 0, 0, 0);
        }
    }

    // ---- write partials (unnormalized O^T + m,l) ----
    int slot = jh * 4 + n;
    if (quad == 0) {
#pragma unroll
        for (int mt = 0; mt < 2; mt++) {
            int i = i0 + w * 32 + mt * 16 + l16;
            g_ml[(slot * 2 + 0) * HW + i] = m_[mt];
            g_ml[(slot * 2 + 1) * HW + i] = l_[mt];
        }
    }
    float* ob = g_opart + slot * CHW;
#pragma unroll
    for (int mt = 0; mt < 2; mt++) {
        int ig = i0 + w * 32 + mt * 16 + l16;
#pragma unroll
        for (int ct = 0; ct < 16; ct++)
#pragma unroll
            for (int r = 0; r < 4; r++) {
                int c = ct * 16 + quad * 4 + r;
                ob[c * HW + ig] = o_acc[mt][ct][r];
            }
    }
}

// ---------------- kernel 4: merge j-halves + residual + store ----------------
__global__ __launch_bounds__(256) void k_combine(
    const void* __restrict__ xv, const void* __restrict__ gv, void* __restrict__ outv)
{
    int mode = g_mode[0];
    float gam = fin0(mode ? ((const float*)gv)[0] : bf2f(((const ushort_t*)gv)[0]));
    int n = blockIdx.y;
    int base = blockIdx.x * 1024;
    const float* mlb0 = g_ml + ((0 * 4 + n) * 2) * HW;
    const float* mlb1 = g_ml + ((1 * 4 + n) * 2) * HW;
    const float* ob0 = g_opart + (0 * 4 + n) * CHW;
    const float* ob1 = g_opart + (1 * 4 + n) * CHW;
#pragma unroll
    for (int e = 0; e < 4; ++e) {
        int off = base + e * 256 + threadIdx.x;
        int i = off & (HW - 1);
        float m0 = mlb0[i], l0 = mlb0[HW + i];
        float m1 = mlb1[i], l1 = mlb1[HW + i];
        float m = fmaxf(m0, m1);
        float w0 = __builtin_amdgcn_exp2f((m0 - m) * L2E);
        float w1 = __builtin_amdgcn_exp2f((m1 - m) * L2E);
        float l = w0 * l0 + w1 * l1;
        float inv = (l > 1e-30f) ? 1.0f / l : 0.f;
        float o = (w0 * ob0[off] + w1 * ob1[off]) * inv;
        if (mode == 0) {
            float xvv = bf2f(((const ushort_t*)xv)[n * CHW + off]);
            ((ushort_t*)outv)[n * CHW + off] = f2bf(fin0(xvv + gam * o));
        } else {
            float xvv = ((const float*)xv)[n * CHW + off];
            ((float*)outv)[n * CHW + off] = fin0(xvv + gam * o);
        }
    }
}

extern "C" void kernel_launch(void* const* d_in, const int* in_sizes, int n_in,
                              void* d_out, int out_size, void* d_ws, size_t ws_size,
                              hipStream_t stream) {
    (void)d_ws; (void)ws_size;
    bool ok = (n_in == 8) &&
              in_sizes[0] == 4 * CHW &&
              in_sizes[1] == C_DIM * C_DIM && in_sizes[2] == C_DIM &&
              in_sizes[3] == C_DIM * C_DIM && in_sizes[4] == C_DIM &&
              in_sizes[5] == C_DIM * C_DIM && in_sizes[6] == C_DIM &&
              in_sizes[7] == 1 && out_size == 4 * CHW;
    if (!ok) {
        hipLaunchKernelGGL(k_sentinel, dim3((out_size + 255) / 256), dim3(256), 0, stream,
                           (ushort_t*)d_out, out_size);
        return;
    }
    hipLaunchKernelGGL(k_probe, dim3(1), dim3(64), 0, stream, d_in[0]);
    hipLaunchKernelGGL(k_transpose, dim3(64, 4, 4), dim3(256), 0, stream, d_in[0]);
    hipLaunchKernelGGL(k_proj, dim3(32, 6, 4), dim3(256), 0, stream,
                       d_in[1], d_in[2], d_in[3], d_in[4], d_in[5], d_in[6]);
    hipLaunchKernelGGL(k_attn, dim3(512), dim3(128), 0, stream);
    hipLaunchKernelGGL(k_combine, dim3(CHW / 1024, 4), dim3(256), 0, stream,
                       d_in[0], d_in[7], d_out);
}

// Round 9
// 296.141 us; speedup vs baseline: 2.0331x; 1.0284x over previous
//
#include <hip/hip_runtime.h>

typedef unsigned short ushort_t;
typedef unsigned int u32;
typedef _Float16 f16;
typedef f16 f16x8 __attribute__((ext_vector_type(8)));
typedef f16 f16x2 __attribute__((ext_vector_type(2)));
typedef ushort_t u16x8 __attribute__((ext_vector_type(8)));
typedef float f32x4 __attribute__((ext_vector_type(4)));

#define C_DIM 256
#define HW 4096
#define CHW (C_DIM*HW)
#define L2E 1.4426950408889634f

// Device-global scratch. Internal pipeline f16.
__device__ __align__(16) f16 g_xbT[4 * CHW];
__device__ __align__(16) f16 g_q[4 * CHW];
__device__ __align__(16) f16 g_k[4 * CHW];
__device__ __align__(16) f16 g_v[4 * CHW];
__device__ __align__(16) f16 g_opart[16 * CHW];   // [slot=jq*4+n][c][i] normalized O^T
__device__ float g_ml[16 * 2 * HW];               // [slot][{m,l}][i]
__device__ int g_mode[1];   // 0 = inputs bf16, 1 = inputs f32

__device__ __forceinline__ float bf2f(ushort_t h) {
    union { u32 u; float f; } v; v.u = ((u32)h) << 16; return v.f;
}
__device__ __forceinline__ ushort_t f2bf(float f) {
    union { float f; u32 u; } v; v.f = f;
    u32 r = v.u + 0x7FFF + ((v.u >> 16) & 1);
    return (ushort_t)(r >> 16);
}
__device__ __forceinline__ float fin0(float v) {
    return (v > -1e30f && v < 1e30f) ? v : 0.f;
}
__device__ __forceinline__ f16 sf16(float v) {
    return (f16)((v > -1e4f && v < 1e4f) ? v : 0.f);
}
__device__ __forceinline__ void gl2lds16(const f16* g, f16* l) {
    __builtin_amdgcn_global_load_lds(
        (const __attribute__((address_space(1))) u32*)g,
        (__attribute__((address_space(3))) u32*)l, 16, 0, 0);
}

// ---------------- kernel 0: dtype probe ----------------
__global__ void k_probe(const void* __restrict__ xv) {
    const ushort_t* xh = (const ushort_t*)xv;
    int lane = threadIdx.x;
    float s = 0.f;
    for (int i = lane; i < 2048; i += 64) {
        float v = fabsf(bf2f(xh[i]));
        v = (v < 1e6f) ? v : 1e6f;
        s += v;
    }
#pragma unroll
    for (int d = 1; d < 64; d <<= 1) s += __shfl_xor(s, d, 64);
    if (lane == 0) g_mode[0] = (s * (1.f / 2048.f) > 100.f) ? 1 : 0;
}

__global__ void k_sentinel(ushort_t* out, int n) {
    int i = blockIdx.x * 256 + threadIdx.x;
    if (i < n) out[i] = f2bf(777.f);
}

// ---------------- kernel 1: x (N,C,HW) -> g_xbT f16 (N,HW,C) ----------------
__global__ __launch_bounds__(256) void k_transpose(const void* __restrict__ xv) {
    __shared__ f16 t[64][66];
    int mode = g_mode[0];
    int n = blockIdx.z, c0 = blockIdx.y * 64, l0 = blockIdx.x * 64;
    int tid = threadIdx.x;
    f16* ob = g_xbT + n * CHW;
    int lq = (tid & 15) * 4;
    int cl = tid >> 4;
    if (mode == 0) {
        const ushort_t* xb = (const ushort_t*)xv + n * CHW;
#pragma unroll
        for (int p = 0; p < 4; ++p) {
            int c = cl + 16 * p;
            ushort4 v = *(const ushort4*)(xb + (c0 + c) * HW + l0 + lq);
            t[lq + 0][c] = sf16(bf2f(v.x));
            t[lq + 1][c] = sf16(bf2f(v.y));
            t[lq + 2][c] = sf16(bf2f(v.z));
            t[lq + 3][c] = sf16(bf2f(v.w));
        }
    } else {
        const float* xb = (const float*)xv + n * CHW;
#pragma unroll
        for (int p = 0; p < 4; ++p) {
            int c = cl + 16 * p;
            float4 v = *(const float4*)(xb + (c0 + c) * HW + l0 + lq);
            t[lq + 0][c] = sf16(v.x);
            t[lq + 1][c] = sf16(v.y);
            t[lq + 2][c] = sf16(v.z);
            t[lq + 3][c] = sf16(v.w);
        }
    }
    __syncthreads();
    int c2 = (tid & 31) * 2;
    int lr = tid >> 5;
#pragma unroll
    for (int p = 0; p < 8; ++p) {
        int l = lr + 8 * p;
        u32 pair = *(const u32*)&t[l][c2];
        *(u32*)(ob + (l0 + l) * C_DIM + c0 + c2) = pair;
    }
}

// ---------------- kernel 2: projections (f16 MFMA) ----------------
__global__ __launch_bounds__(256) void k_proj(
    const void* __restrict__ Wq, const void* __restrict__ bq,
    const void* __restrict__ Wk, const void* __restrict__ bk,
    const void* __restrict__ Wv, const void* __restrict__ bv)
{
    __shared__ __align__(16) f16 lds_x[128 * 64];
    __shared__ __align__(16) f16 lds_w[128 * 64];
    int mode = g_mode[0];
    int l0 = blockIdx.x * 128;
    int og0 = blockIdx.y * 128;
    int n = blockIdx.z;
    int mat = og0 >> 8;       // 0=q,1=k,2=v
    int om0 = og0 & 255;
    const void* W = (mat == 0) ? Wq : (mat == 1) ? Wk : Wv;
    const void* bias = (mat == 0) ? bq : (mat == 1) ? bk : bv;
    int tid = threadIdx.x, w = tid >> 6, lane = tid & 63;
    int quad = lane >> 4, l16 = lane & 15;
    const f16* xb = g_xbT + n * CHW;

    f32x4 acc[2][8];
#pragma unroll
    for (int a = 0; a < 2; a++)
#pragma unroll
        for (int b = 0; b < 8; b++) acc[a][b] = f32x4{0.f, 0.f, 0.f, 0.f};

    for (int ch = 0; ch < 4; ++ch) {
        int cc0 = ch * 64;
        f16x8 xs[4], wsr[4];
#pragma unroll
        for (int ti = 0; ti < 4; ++ti) {
            int s = (w * 4 + ti) * 64 + lane;
            int row = s >> 3, gp = s & 7;
            xs[ti] = *(const f16x8*)(xb + (l0 + row) * C_DIM + cc0 + gp * 8);
            f16x8 h;
            if (mode == 0) {
                u16x8 wv = *(const u16x8*)((const ushort_t*)W + (om0 + row) * C_DIM + cc0 + gp * 8);
#pragma unroll
                for (int e = 0; e < 8; e++) h[e] = sf16(bf2f(wv[e]));
            } else {
                const float* wf = (const float*)W + (om0 + row) * C_DIM + cc0 + gp * 8;
#pragma unroll
                for (int e = 0; e < 8; e++) h[e] = sf16(wf[e]);
            }
            wsr[ti] = h;
        }
        __syncthreads();
#pragma unroll
        for (int ti = 0; ti < 4; ++ti) {
            int s = (w * 4 + ti) * 64 + lane;
            int row = s >> 3, gp = s & 7;
            int pos = gp ^ (row & 7);
            *(f16x8*)(lds_x + (row * 8 + pos) * 8) = xs[ti];
            *(f16x8*)(lds_w + (row * 8 + pos) * 8) = wsr[ti];
        }
        __syncthreads();
#pragma unroll
        for (int ks = 0; ks < 2; ++ks) {
            f16x8 af[2];
#pragma unroll
            for (int mt = 0; mt < 2; ++mt) {
                int row = w * 32 + mt * 16 + l16;
                int g = ks * 4 + quad;
                int pos = g ^ (row & 7);
                af[mt] = *(const f16x8*)(lds_x + (row * 8 + pos) * 8);
            }
#pragma unroll
            for (int nt = 0; nt < 8; ++nt) {
                int rowo = nt * 16 + l16;
                int g = ks * 4 + quad;
                int pos = g ^ (rowo & 7);
                f16x8 bfv = *(const f16x8*)(lds_w + (rowo * 8 + pos) * 8);
                if (mat < 2) {
                    acc[0][nt] = __builtin_amdgcn_mfma_f32_16x16x32_f16(af[0], bfv, acc[0][nt], 0, 0, 0);
                    acc[1][nt] = __builtin_amdgcn_mfma_f32_16x16x32_f16(af[1], bfv, acc[1][nt], 0, 0, 0);
                } else {
                    acc[0][nt] = __builtin_amdgcn_mfma_f32_16x16x32_f16(bfv, af[0], acc[0][nt], 0, 0, 0);
                    acc[1][nt] = __builtin_amdgcn_mfma_f32_16x16x32_f16(bfv, af[1], acc[1][nt], 0, 0, 0);
                }
            }
        }
        __syncthreads();
    }

    auto loadb = [&](int i) -> float {
        return mode ? ((const float*)bias)[i] : bf2f(((const ushort_t*)bias)[i]);
    };
    if (mat < 2) {
        f16* T = ((mat == 0) ? g_q : g_k) + n * CHW;
        float bvv[8];
#pragma unroll
        for (int nt = 0; nt < 8; nt++) bvv[nt] = loadb(om0 + nt * 16 + l16);
#pragma unroll
        for (int mt = 0; mt < 2; mt++)
#pragma unroll
            for (int nt = 0; nt < 8; nt++)
#pragma unroll
                for (int r = 0; r < 4; r++) {
                    int l = l0 + w * 32 + mt * 16 + quad * 4 + r;
                    int o = om0 + nt * 16 + l16;
                    T[l * C_DIM + o] = sf16(acc[mt][nt][r] + bvv[nt]);
                }
    } else {
        f16* T = g_v + n * CHW;
#pragma unroll
        for (int mt = 0; mt < 2; mt++)
#pragma unroll
            for (int nt = 0; nt < 8; nt++)
#pragma unroll
                for (int r = 0; r < 4; r++) {
                    int o = om0 + nt * 16 + quad * 4 + r;
                    int l = l0 + w * 32 + mt * 16 + l16;
                    T[o * HW + l] = sf16(acc[mt][nt][r] + loadb(o));
                }
    }
}

// ---------------- kernel 3: flash attention, S^T, BM=128 (4 waves x M=32), split-j x4 ----------------
// 512 blocks x 256 thr. 2 blocks/CU -> 8 waves/CU = 2 waves/SIMD.
// m quantized to multiples of 8 -> o_acc rescale fires only on quantum jumps.
__global__ __launch_bounds__(256, 1) void k_attn() {
    __shared__ __align__(16) char smem[75776];
    f16* kbuf = (f16*)smem;             // 2 x 8192 f16 (32 j x 32 granules, swizzled)
    f16* vbuf = (f16*)(smem + 32768);   // 2 x 8192 f16 (256 c x 4 granules, swizzled)
    f16* pb   = (f16*)(smem + 65536);   // 4 waves x 2 mt x 16 i x 40 f16

    int bid = blockIdx.x;
    int x8 = bid & 7;
    int n = x8 >> 1, jhi = x8 & 1;      // XCD sees fixed (n, j-half)
    int rest = bid >> 3;
    int jlo = rest & 1;
    int i0 = (rest >> 1) * 128;         // 32 i-tiles of BM=128
    int jq = jhi * 2 + jlo;
    int tid = threadIdx.x, w = tid >> 6, lane = tid & 63;
    int quad = lane >> 4, l16 = lane & 15;

    const f16* Qb = g_q + n * CHW;
    const f16* Kb = g_k + n * CHW;
    const f16* Vb = g_v + n * CHW;
    f16* pw = pb + w * 1280;

    // Precomputed LDS read offsets (f16-element units)
    int koff0[8], koff1[8], voff[16];
#pragma unroll
    for (int kk = 0; kk < 8; kk++) {
        int g2 = kk * 4 + quad;
        int pos = (g2 & 24) | ((g2 & 7) ^ (l16 & 7));
        koff0[kk] = (l16 * 32 + pos) * 8;
        koff1[kk] = ((16 + l16) * 32 + pos) * 8;
    }
#pragma unroll
    for (int ct = 0; ct < 16; ct++) {
        int c = ct * 16 + l16;
        voff[ct] = (c * 4 + (quad ^ ((c >> 1) & 3))) * 8;
    }

    // Q fragments (B-operand), 2 i-groups of 16 per wave
    f16x8 qf[2][8];
#pragma unroll
    for (int mt = 0; mt < 2; mt++) {
        const f16* qrow = Qb + (i0 + w * 32 + mt * 16 + l16) * C_DIM + quad * 8;
#pragma unroll
        for (int kk = 0; kk < 8; kk++)
            qf[mt][kk] = *(const f16x8*)(qrow + kk * 32);
    }

    f32x4 o_acc[2][16];
#pragma unroll
    for (int mt = 0; mt < 2; mt++)
#pragma unroll
        for (int i = 0; i < 16; i++) o_acc[mt][i] = f32x4{0.f, 0.f, 0.f, 0.f};
    float m_[2] = {-1e30f, -1e30f}, l_[2] = {0.f, 0.f};

    auto stage = [&](int jt, int buf) {
#pragma unroll
        for (int s = 0; s < 4; ++s) {
            int idx = s * 256 + tid;
            int j = idx >> 5, gp = idx & 31;
            int gg = (gp & 24) | ((gp & 7) ^ (j & 7));
            gl2lds16(Kb + (jt * 32 + j) * C_DIM + gg * 8,
                     kbuf + (buf * 1024 + s * 256 + w * 64) * 8);
        }
#pragma unroll
        for (int s = 0; s < 4; ++s) {
            int idx = s * 256 + tid;
            int c = idx >> 2, jp = idx & 3;
            int jg = jp ^ ((c >> 1) & 3);
            gl2lds16(Vb + c * HW + jt * 32 + jg * 8,
                     vbuf + (buf * 1024 + s * 256 + w * 64) * 8);
        }
    };

    int jt0 = jq * 32;
    stage(jt0, 0);

    for (int it = 0; it < 32; ++it) {
        int buf = it & 1;
        __syncthreads();
        if (it + 1 < 32) stage(jt0 + it + 1, buf ^ 1);

        const f16* kb = kbuf + buf * 8192;
        const f16* vb = vbuf + buf * 8192;

        // ---- S^T = K Q^T : st[mt][jtile], D[j=jtile*16+quad*4+r][i=l16] ----
        f32x4 st[2][2];
        st[0][0] = f32x4{0.f,0.f,0.f,0.f}; st[0][1] = f32x4{0.f,0.f,0.f,0.f};
        st[1][0] = f32x4{0.f,0.f,0.f,0.f}; st[1][1] = f32x4{0.f,0.f,0.f,0.f};
#pragma unroll
        for (int kk = 0; kk < 8; kk++) {
            f16x8 kf0 = *(const f16x8*)(kb + koff0[kk]);
            f16x8 kf1 = *(const f16x8*)(kb + koff1[kk]);
            st[0][0] = __builtin_amdgcn_mfma_f32_16x16x32_f16(kf0, qf[0][kk], st[0][0], 0, 0, 0);
            st[0][1] = __builtin_amdgcn_mfma_f32_16x16x32_f16(kf1, qf[0][kk], st[0][1], 0, 0, 0);
            st[1][0] = __builtin_amdgcn_mfma_f32_16x16x32_f16(kf0, qf[1][kk], st[1][0], 0, 0, 0);
            st[1][1] = __builtin_amdgcn_mfma_f32_16x16x32_f16(kf1, qf[1][kk], st[1][1], 0, 0, 0);
        }

        // ---- per-lane online softmax (column i = l16 of group mt), quantized max ----
        float al[2];
        float pv0[2][4], pv1[2][4];
#pragma unroll
        for (int mt = 0; mt < 2; mt++) {
#pragma unroll
            for (int r = 0; r < 4; r++) {
                float a = st[mt][0][r], b = st[mt][1][r];
                st[mt][0][r] = (a > -1e30f && a < 1e30f) ? a : -30000.f;
                st[mt][1][r] = (b > -1e30f && b < 1e30f) ? b : -30000.f;
            }
            float smax = fmaxf(fmaxf(fmaxf(st[mt][0][0], st[mt][0][1]), fmaxf(st[mt][0][2], st[mt][0][3])),
                               fmaxf(fmaxf(st[mt][1][0], st[mt][1][1]), fmaxf(st[mt][1][2], st[mt][1][3])));
            smax = fmaxf(smax, __shfl_xor(smax, 16, 64));
            smax = fmaxf(smax, __shfl_xor(smax, 32, 64));
            float mq = __builtin_ceilf(smax * 0.125f) * 8.f;   // quantized up
            float mn = fmaxf(m_[mt], mq);
            al[mt] = __builtin_amdgcn_exp2f((m_[mt] - mn) * L2E);
            float rs = 0.f;
#pragma unroll
            for (int r = 0; r < 4; r++) {
                pv0[mt][r] = __builtin_amdgcn_exp2f((st[mt][0][r] - mn) * L2E);
                pv1[mt][r] = __builtin_amdgcn_exp2f((st[mt][1][r] - mn) * L2E);
                rs += pv0[mt][r] + pv1[mt][r];
            }
            m_[mt] = mn;
            rs += __shfl_xor(rs, 16, 64);
            rs += __shfl_xor(rs, 32, 64);
            l_[mt] = l_[mt] * al[mt] + rs;
        }
        if (__any((al[0] < 1.0f) || (al[1] < 1.0f))) {
#pragma unroll
            for (int mt = 0; mt < 2; mt++)
#pragma unroll
                for (int t = 0; t < 16; t++) o_acc[mt][t] *= al[mt];
        }

        // ---- P^T to LDS [i][j], read back as B-frag ----
#pragma unroll
        for (int mt = 0; mt < 2; mt++) {
            f16* pm = pw + mt * 640 + l16 * 40;
            *(f16x2*)(pm + quad * 4)          = f16x2{(f16)pv0[mt][0], (f16)pv0[mt][1]};
            *(f16x2*)(pm + quad * 4 + 2)      = f16x2{(f16)pv0[mt][2], (f16)pv0[mt][3]};
            *(f16x2*)(pm + 16 + quad * 4)     = f16x2{(f16)pv1[mt][0], (f16)pv1[mt][1]};
            *(f16x2*)(pm + 16 + quad * 4 + 2) = f16x2{(f16)pv1[mt][2], (f16)pv1[mt][3]};
        }
        asm volatile("" ::: "memory");
        f16x8 pf0 = *(const f16x8*)(pw + l16 * 40 + quad * 8);
        f16x8 pf1 = *(const f16x8*)(pw + 640 + l16 * 40 + quad * 8);

        // ---- O^T += V P^T : each vf feeds both i-groups ----
#pragma unroll
        for (int ct = 0; ct < 16; ++ct) {
            f16x8 vf = *(const f16x8*)(vb + voff[ct]);
            o_acc[0][ct] = __builtin_amdgcn_mfma_f32_16x16x32_f16(vf, pf0, o_acc[0][ct], 0, 0, 0);
            o_acc[1][ct] = __builtin_amdgcn_mfma_f32_16x16x32_f16(vf, pf1, o_acc[1][ct], 0, 0, 0);
        }
    }

    // ---- write partials: normalized O^T (f16) + m,l (f32) ----
    int slot = jq * 4 + n;
    if (quad == 0) {
#pragma unroll
        for (int mt = 0; mt < 2; mt++) {
            int i = i0 + w * 32 + mt * 16 + l16;
            g_ml[(slot * 2 + 0) * HW + i] = m_[mt];
            g_ml[(slot * 2 + 1) * HW + i] = l_[mt];
        }
    }
    f16* ob = g_opart + slot * CHW;
#pragma unroll
    for (int mt = 0; mt < 2; mt++) {
        int ig = i0 + w * 32 + mt * 16 + l16;
        float inv = (l_[mt] > 1e-30f) ? 1.0f / l_[mt] : 0.f;
#pragma unroll
        for (int ct = 0; ct < 16; ct++)
#pragma unroll
            for (int r = 0; r < 4; r++) {
                int c = ct * 16 + quad * 4 + r;
                ob[c * HW + ig] = (f16)(o_acc[mt][ct][r] * inv);
            }
    }
}

// ---------------- kernel 4: merge 4 j-quarters + residual + store ----------------
__global__ __launch_bounds__(256) void k_combine(
    const void* __restrict__ xv, const void* __restrict__ gv, void* __restrict__ outv)
{
    int mode = g_mode[0];
    float gam = fin0(mode ? ((const float*)gv)[0] : bf2f(((const ushort_t*)gv)[0]));
    int n = blockIdx.y;
    int base = blockIdx.x * 1024;
#pragma unroll
    for (int e = 0; e < 4; ++e) {
        int off = base + e * 256 + threadIdx.x;
        int i = off & (HW - 1);
        float m = -1e30f;
        float ms[4], ls[4];
#pragma unroll
        for (int s = 0; s < 4; ++s) {
            int slot = s * 4 + n;
            ms[s] = g_ml[(slot * 2 + 0) * HW + i];
            ls[s] = g_ml[(slot * 2 + 1) * HW + i];
            m = fmaxf(m, ms[s]);
        }
        float num = 0.f, den = 0.f;
#pragma unroll
        for (int s = 0; s < 4; ++s) {
            int slot = s * 4 + n;
            float wgt = __builtin_amdgcn_exp2f((ms[s] - m) * L2E) * ls[s];
            num += wgt * (float)((const f16*)g_opart)[slot * CHW + off];
            den += wgt;
        }
        float o = (den > 1e-30f) ? num / den : 0.f;
        if (mode == 0) {
            float xvv = bf2f(((const ushort_t*)xv)[n * CHW + off]);
            ((ushort_t*)outv)[n * CHW + off] = f2bf(fin0(xvv + gam * o));
        } else {
            float xvv = ((const float*)xv)[n * CHW + off];
            ((float*)outv)[n * CHW + off] = fin0(xvv + gam * o);
        }
    }
}

extern "C" void kernel_launch(void* const* d_in, const int* in_sizes, int n_in,
                              void* d_out, int out_size, void* d_ws, size_t ws_size,
                              hipStream_t stream) {
    (void)d_ws; (void)ws_size;
    bool ok = (n_in == 8) &&
              in_sizes[0] == 4 * CHW &&
              in_sizes[1] == C_DIM * C_DIM && in_sizes[2] == C_DIM &&
              in_sizes[3] == C_DIM * C_DIM && in_sizes[4] == C_DIM &&
              in_sizes[5] == C_DIM * C_DIM && in_sizes[6] == C_DIM &&
              in_sizes[7] == 1 && out_size == 4 * CHW;
    if (!ok) {
        hipLaunchKernelGGL(k_sentinel, dim3((out_size + 255) / 256), dim3(256), 0, stream,
                           (ushort_t*)d_out, out_size);
        return;
    }
    hipLaunchKernelGGL(k_probe, dim3(1), dim3(64), 0, stream, d_in[0]);
    hipLaunchKernelGGL(k_transpose, dim3(64, 4, 4), dim3(256), 0, stream, d_in[0]);
    hipLaunchKernelGGL(k_proj, dim3(32, 6, 4), dim3(256), 0, stream,
                       d_in[1], d_in[2], d_in[3], d_in[4], d_in[5], d_in[6]);
    hipLaunchKernelGGL(k_attn, dim3(512), dim3(256), 0, stream);
    hipLaunchKernelGGL(k_combine, dim3(CHW / 1024, 4), dim3(256), 0, stream,
                       d_in[0], d_in[7], d_out);
}

// Round 10
// 283.086 us; speedup vs baseline: 2.1269x; 1.0461x over previous
//
#include <hip/hip_runtime.h>

typedef unsigned short ushort_t;
typedef unsigned int u32;
typedef _Float16 f16;
typedef f16 f16x8 __attribute__((ext_vector_type(8)));
typedef f16 f16x2 __attribute__((ext_vector_type(2)));
typedef ushort_t u16x8 __attribute__((ext_vector_type(8)));
typedef float f32x4 __attribute__((ext_vector_type(4)));

#define C_DIM 256
#define HW 4096
#define CHW (C_DIM*HW)
#define L2E 1.4426950408889634f

// Device-global scratch. Internal pipeline f16.
__device__ __align__(16) f16 g_xbT[4 * CHW];
__device__ __align__(16) f16 g_q[4 * CHW];
__device__ __align__(16) f16 g_k[4 * CHW];
__device__ __align__(16) f16 g_v[4 * CHW];
__device__ __align__(16) f16 g_opart[16 * CHW];   // [slot=jq*4+n][c][i] normalized O^T
__device__ float g_ml[16 * 2 * HW];               // [slot][{m,l}][i]
__device__ int g_mode[1];   // 0 = inputs bf16, 1 = inputs f32

__device__ __forceinline__ float bf2f(ushort_t h) {
    union { u32 u; float f; } v; v.u = ((u32)h) << 16; return v.f;
}
__device__ __forceinline__ ushort_t f2bf(float f) {
    union { float f; u32 u; } v; v.f = f;
    u32 r = v.u + 0x7FFF + ((v.u >> 16) & 1);
    return (ushort_t)(r >> 16);
}
__device__ __forceinline__ float fin0(float v) {
    return (v > -1e30f && v < 1e30f) ? v : 0.f;
}
__device__ __forceinline__ f16 sf16(float v) {
    return (f16)((v > -1e4f && v < 1e4f) ? v : 0.f);
}
__device__ __forceinline__ void gl2lds16(const f16* g, f16* l) {
    __builtin_amdgcn_global_load_lds(
        (const __attribute__((address_space(1))) u32*)g,
        (__attribute__((address_space(3))) u32*)l, 16, 0, 0);
}

// ---------------- kernel 0: dtype probe ----------------
__global__ void k_probe(const void* __restrict__ xv) {
    const ushort_t* xh = (const ushort_t*)xv;
    int lane = threadIdx.x;
    float s = 0.f;
    for (int i = lane; i < 2048; i += 64) {
        float v = fabsf(bf2f(xh[i]));
        v = (v < 1e6f) ? v : 1e6f;
        s += v;
    }
#pragma unroll
    for (int d = 1; d < 64; d <<= 1) s += __shfl_xor(s, d, 64);
    if (lane == 0) g_mode[0] = (s * (1.f / 2048.f) > 100.f) ? 1 : 0;
}

__global__ void k_sentinel(ushort_t* out, int n) {
    int i = blockIdx.x * 256 + threadIdx.x;
    if (i < n) out[i] = f2bf(777.f);
}

// ---------------- kernel 1: x (N,C,HW) -> g_xbT f16 (N,HW,C) ----------------
__global__ __launch_bounds__(256) void k_transpose(const void* __restrict__ xv) {
    __shared__ f16 t[64][66];
    int mode = g_mode[0];
    int n = blockIdx.z, c0 = blockIdx.y * 64, l0 = blockIdx.x * 64;
    int tid = threadIdx.x;
    f16* ob = g_xbT + n * CHW;
    int lq = (tid & 15) * 4;
    int cl = tid >> 4;
    if (mode == 0) {
        const ushort_t* xb = (const ushort_t*)xv + n * CHW;
#pragma unroll
        for (int p = 0; p < 4; ++p) {
            int c = cl + 16 * p;
            ushort4 v = *(const ushort4*)(xb + (c0 + c) * HW + l0 + lq);
            t[lq + 0][c] = sf16(bf2f(v.x));
            t[lq + 1][c] = sf16(bf2f(v.y));
            t[lq + 2][c] = sf16(bf2f(v.z));
            t[lq + 3][c] = sf16(bf2f(v.w));
        }
    } else {
        const float* xb = (const float*)xv + n * CHW;
#pragma unroll
        for (int p = 0; p < 4; ++p) {
            int c = cl + 16 * p;
            float4 v = *(const float4*)(xb + (c0 + c) * HW + l0 + lq);
            t[lq + 0][c] = sf16(v.x);
            t[lq + 1][c] = sf16(v.y);
            t[lq + 2][c] = sf16(v.z);
            t[lq + 3][c] = sf16(v.w);
        }
    }
    __syncthreads();
    int c2 = (tid & 31) * 2;
    int lr = tid >> 5;
#pragma unroll
    for (int p = 0; p < 8; ++p) {
        int l = lr + 8 * p;
        u32 pair = *(const u32*)&t[l][c2];
        *(u32*)(ob + (l0 + l) * C_DIM + c0 + c2) = pair;
    }
}

// ---------------- kernel 2: projections (f16 MFMA) ----------------
__global__ __launch_bounds__(256) void k_proj(
    const void* __restrict__ Wq, const void* __restrict__ bq,
    const void* __restrict__ Wk, const void* __restrict__ bk,
    const void* __restrict__ Wv, const void* __restrict__ bv)
{
    __shared__ __align__(16) f16 lds_x[128 * 64];
    __shared__ __align__(16) f16 lds_w[128 * 64];
    int mode = g_mode[0];
    int l0 = blockIdx.x * 128;
    int og0 = blockIdx.y * 128;
    int n = blockIdx.z;
    int mat = og0 >> 8;       // 0=q,1=k,2=v
    int om0 = og0 & 255;
    const void* W = (mat == 0) ? Wq : (mat == 1) ? Wk : Wv;
    const void* bias = (mat == 0) ? bq : (mat == 1) ? bk : bv;
    int tid = threadIdx.x, w = tid >> 6, lane = tid & 63;
    int quad = lane >> 4, l16 = lane & 15;
    const f16* xb = g_xbT + n * CHW;

    f32x4 acc[2][8];
#pragma unroll
    for (int a = 0; a < 2; a++)
#pragma unroll
        for (int b = 0; b < 8; b++) acc[a][b] = f32x4{0.f, 0.f, 0.f, 0.f};

    for (int ch = 0; ch < 4; ++ch) {
        int cc0 = ch * 64;
        f16x8 xs[4], wsr[4];
#pragma unroll
        for (int ti = 0; ti < 4; ++ti) {
            int s = (w * 4 + ti) * 64 + lane;
            int row = s >> 3, gp = s & 7;
            xs[ti] = *(const f16x8*)(xb + (l0 + row) * C_DIM + cc0 + gp * 8);
            f16x8 h;
            if (mode == 0) {
                u16x8 wv = *(const u16x8*)((const ushort_t*)W + (om0 + row) * C_DIM + cc0 + gp * 8);
#pragma unroll
                for (int e = 0; e < 8; e++) h[e] = sf16(bf2f(wv[e]));
            } else {
                const float* wf = (const float*)W + (om0 + row) * C_DIM + cc0 + gp * 8;
#pragma unroll
                for (int e = 0; e < 8; e++) h[e] = sf16(wf[e]);
            }
            wsr[ti] = h;
        }
        __syncthreads();
#pragma unroll
        for (int ti = 0; ti < 4; ++ti) {
            int s = (w * 4 + ti) * 64 + lane;
            int row = s >> 3, gp = s & 7;
            int pos = gp ^ (row & 7);
            *(f16x8*)(lds_x + (row * 8 + pos) * 8) = xs[ti];
            *(f16x8*)(lds_w + (row * 8 + pos) * 8) = wsr[ti];
        }
        __syncthreads();
#pragma unroll
        for (int ks = 0; ks < 2; ++ks) {
            f16x8 af[2];
#pragma unroll
            for (int mt = 0; mt < 2; ++mt) {
                int row = w * 32 + mt * 16 + l16;
                int g = ks * 4 + quad;
                int pos = g ^ (row & 7);
                af[mt] = *(const f16x8*)(lds_x + (row * 8 + pos) * 8);
            }
#pragma unroll
            for (int nt = 0; nt < 8; ++nt) {
                int rowo = nt * 16 + l16;
                int g = ks * 4 + quad;
                int pos = g ^ (rowo & 7);
                f16x8 bfv = *(const f16x8*)(lds_w + (rowo * 8 + pos) * 8);
                if (mat < 2) {
                    acc[0][nt] = __builtin_amdgcn_mfma_f32_16x16x32_f16(af[0], bfv, acc[0][nt], 0, 0, 0);
                    acc[1][nt] = __builtin_amdgcn_mfma_f32_16x16x32_f16(af[1], bfv, acc[1][nt], 0, 0, 0);
                } else {
                    acc[0][nt] = __builtin_amdgcn_mfma_f32_16x16x32_f16(bfv, af[0], acc[0][nt], 0, 0, 0);
                    acc[1][nt] = __builtin_amdgcn_mfma_f32_16x16x32_f16(bfv, af[1], acc[1][nt], 0, 0, 0);
                }
            }
        }
        __syncthreads();
    }

    auto loadb = [&](int i) -> float {
        return mode ? ((const float*)bias)[i] : bf2f(((const ushort_t*)bias)[i]);
    };
    if (mat < 2) {
        f16* T = ((mat == 0) ? g_q : g_k) + n * CHW;
        float bvv[8];
#pragma unroll
        for (int nt = 0; nt < 8; nt++) bvv[nt] = loadb(om0 + nt * 16 + l16);
#pragma unroll
        for (int mt = 0; mt < 2; mt++)
#pragma unroll
            for (int nt = 0; nt < 8; nt++)
#pragma unroll
                for (int r = 0; r < 4; r++) {
                    int l = l0 + w * 32 + mt * 16 + quad * 4 + r;
                    int o = om0 + nt * 16 + l16;
                    T[l * C_DIM + o] = sf16(acc[mt][nt][r] + bvv[nt]);
                }
    } else {
        f16* T = g_v + n * CHW;
#pragma unroll
        for (int mt = 0; mt < 2; mt++)
#pragma unroll
            for (int nt = 0; nt < 8; nt++)
#pragma unroll
                for (int r = 0; r < 4; r++) {
                    int o = om0 + nt * 16 + quad * 4 + r;
                    int l = l0 + w * 32 + mt * 16 + l16;
                    T[o * HW + l] = sf16(acc[mt][nt][r] + loadb(o));
                }
    }
}

// ---------------- kernel 3: flash attention, S^T, BM=128, split-j x4 ----------------
// 512 blocks x 256 thr. LDS 58 KB -> 2 blocks/CU co-resident (2 waves/SIMD).
// K double-buffered via global_load_lds; V single-buffered via register staging.
__global__ __launch_bounds__(256, 2) void k_attn() {
    __shared__ __align__(16) char smem[59392];
    f16* kbuf = (f16*)smem;             // 2 x 8192 f16 (32 j x 32 granules, swizzled)
    f16* vbuf = (f16*)(smem + 32768);   // 8192 f16 (256 c x 4 granules, swizzled)
    f16* pb   = (f16*)(smem + 49152);   // 4 waves x 2 mt x 16 i x 40 f16

    int bid = blockIdx.x;
    int x8 = bid & 7;
    int n = x8 >> 1, jhi = x8 & 1;      // XCD sees fixed (n, j-half)
    int rest = bid >> 3;
    int jlo = rest & 1;
    int i0 = (rest >> 1) * 128;         // 32 i-tiles of BM=128
    int jq = jhi * 2 + jlo;
    int tid = threadIdx.x, w = tid >> 6, lane = tid & 63;
    int quad = lane >> 4, l16 = lane & 15;

    const f16* Qb = g_q + n * CHW;
    const f16* Kb = g_k + n * CHW;
    const f16* Vb = g_v + n * CHW;
    f16* pw = pb + w * 1280;

    // Precomputed LDS read offsets (f16-element units)
    int koff0[8], koff1[8], voff[16];
#pragma unroll
    for (int kk = 0; kk < 8; kk++) {
        int g2 = kk * 4 + quad;
        int pos = (g2 & 24) | ((g2 & 7) ^ (l16 & 7));
        koff0[kk] = (l16 * 32 + pos) * 8;
        koff1[kk] = ((16 + l16) * 32 + pos) * 8;
    }
#pragma unroll
    for (int ct = 0; ct < 16; ct++) {
        int c = ct * 16 + l16;
        voff[ct] = (c * 4 + (quad ^ ((c >> 1) & 3))) * 8;
    }

    // Q fragments (B-operand), 2 i-groups of 16 per wave
    f16x8 qf[2][8];
#pragma unroll
    for (int mt = 0; mt < 2; mt++) {
        const f16* qrow = Qb + (i0 + w * 32 + mt * 16 + l16) * C_DIM + quad * 8;
#pragma unroll
        for (int kk = 0; kk < 8; kk++)
            qf[mt][kk] = *(const f16x8*)(qrow + kk * 32);
    }

    f32x4 o_acc[2][16];
#pragma unroll
    for (int mt = 0; mt < 2; mt++)
#pragma unroll
        for (int i = 0; i < 16; i++) o_acc[mt][i] = f32x4{0.f, 0.f, 0.f, 0.f};
    float m_[2] = {-1e30f, -1e30f}, l_[2] = {0.f, 0.f};

    auto stageK = [&](int jt, int buf) {
#pragma unroll
        for (int s = 0; s < 4; ++s) {
            int idx = s * 256 + tid;
            int j = idx >> 5, gp = idx & 31;
            int gg = (gp & 24) | ((gp & 7) ^ (j & 7));
            gl2lds16(Kb + (jt * 32 + j) * C_DIM + gg * 8,
                     kbuf + (buf * 1024 + s * 256 + w * 64) * 8);
        }
    };
    // V register staging: per-thread 4 granules (swizzle in global address)
    f16x8 vreg[4];
    int vgoff[4], vloff[4];
#pragma unroll
    for (int s = 0; s < 4; ++s) {
        int idx = s * 256 + tid;
        int c = idx >> 2, jp = idx & 3;
        int jg = jp ^ ((c >> 1) & 3);
        vgoff[s] = c * HW + jg * 8;
        vloff[s] = idx * 8;
    }
    auto loadV = [&](int jt) {
#pragma unroll
        for (int s = 0; s < 4; ++s)
            vreg[s] = *(const f16x8*)(Vb + vgoff[s] + jt * 32);
    };
    auto writeV = [&]() {
#pragma unroll
        for (int s = 0; s < 4; ++s)
            *(f16x8*)(vbuf + vloff[s]) = vreg[s];
    };

    int jt0 = jq * 32;
    stageK(jt0, 0);
    loadV(jt0);
    writeV();
    __syncthreads();   // K(0) drained, V(0) visible

    for (int it = 0; it < 32; ++it) {
        int buf = it & 1;
        if (it + 1 < 32) {
            stageK(jt0 + it + 1, buf ^ 1);  // async into other K buffer
            loadV(jt0 + it + 1);            // V prefetch into registers
        }

        const f16* kb = kbuf + buf * 8192;

        // ---- S^T = K Q^T : st[mt][jtile], D[j=jtile*16+quad*4+r][i=l16] ----
        f32x4 st[2][2];
        st[0][0] = f32x4{0.f,0.f,0.f,0.f}; st[0][1] = f32x4{0.f,0.f,0.f,0.f};
        st[1][0] = f32x4{0.f,0.f,0.f,0.f}; st[1][1] = f32x4{0.f,0.f,0.f,0.f};
#pragma unroll
        for (int kk = 0; kk < 8; kk++) {
            f16x8 kf0 = *(const f16x8*)(kb + koff0[kk]);
            f16x8 kf1 = *(const f16x8*)(kb + koff1[kk]);
            st[0][0] = __builtin_amdgcn_mfma_f32_16x16x32_f16(kf0, qf[0][kk], st[0][0], 0, 0, 0);
            st[0][1] = __builtin_amdgcn_mfma_f32_16x16x32_f16(kf1, qf[0][kk], st[0][1], 0, 0, 0);
            st[1][0] = __builtin_amdgcn_mfma_f32_16x16x32_f16(kf0, qf[1][kk], st[1][0], 0, 0, 0);
            st[1][1] = __builtin_amdgcn_mfma_f32_16x16x32_f16(kf1, qf[1][kk], st[1][1], 0, 0, 0);
        }

        // ---- per-lane online softmax (column i = l16 of group mt), quantized max ----
        float al[2];
        float pv0[2][4], pv1[2][4];
#pragma unroll
        for (int mt = 0; mt < 2; mt++) {
            float smax = fmaxf(fmaxf(fmaxf(st[mt][0][0], st[mt][0][1]), fmaxf(st[mt][0][2], st[mt][0][3])),
                               fmaxf(fmaxf(st[mt][1][0], st[mt][1][1]), fmaxf(st[mt][1][2], st[mt][1][3])));
            smax = fmaxf(smax, __shfl_xor(smax, 16, 64));
            smax = fmaxf(smax, __shfl_xor(smax, 32, 64));
            float mq = __builtin_ceilf(smax * 0.125f) * 8.f;   // quantized up
            float mn = fmaxf(m_[mt], mq);
            al[mt] = __builtin_amdgcn_exp2f((m_[mt] - mn) * L2E);
            float rs = 0.f;
#pragma unroll
            for (int r = 0; r < 4; r++) {
                pv0[mt][r] = __builtin_amdgcn_exp2f((st[mt][0][r] - mn) * L2E);
                pv1[mt][r] = __builtin_amdgcn_exp2f((st[mt][1][r] - mn) * L2E);
                rs += pv0[mt][r] + pv1[mt][r];
            }
            m_[mt] = mn;
            rs += __shfl_xor(rs, 16, 64);
            rs += __shfl_xor(rs, 32, 64);
            l_[mt] = l_[mt] * al[mt] + rs;
        }
        if (__any((al[0] < 1.0f) || (al[1] < 1.0f))) {
#pragma unroll
            for (int mt = 0; mt < 2; mt++)
#pragma unroll
                for (int t = 0; t < 16; t++) o_acc[mt][t] *= al[mt];
        }

        // ---- P^T to LDS [i][j], read back as B-frag ----
#pragma unroll
        for (int mt = 0; mt < 2; mt++) {
            f16* pm = pw + mt * 640 + l16 * 40;
            *(f16x2*)(pm + quad * 4)          = f16x2{(f16)pv0[mt][0], (f16)pv0[mt][1]};
            *(f16x2*)(pm + quad * 4 + 2)      = f16x2{(f16)pv0[mt][2], (f16)pv0[mt][3]};
            *(f16x2*)(pm + 16 + quad * 4)     = f16x2{(f16)pv1[mt][0], (f16)pv1[mt][1]};
            *(f16x2*)(pm + 16 + quad * 4 + 2) = f16x2{(f16)pv1[mt][2], (f16)pv1[mt][3]};
        }
        asm volatile("" ::: "memory");
        f16x8 pf0 = *(const f16x8*)(pw + l16 * 40 + quad * 8);
        f16x8 pf1 = *(const f16x8*)(pw + 640 + l16 * 40 + quad * 8);

        // ---- O^T += V P^T : each vf feeds both i-groups ----
#pragma unroll
        for (int ct = 0; ct < 16; ++ct) {
            f16x8 vf = *(const f16x8*)(vbuf + voff[ct]);
            o_acc[0][ct] = __builtin_amdgcn_mfma_f32_16x16x32_f16(vf, pf0, o_acc[0][ct], 0, 0, 0);
            o_acc[1][ct] = __builtin_amdgcn_mfma_f32_16x16x32_f16(vf, pf1, o_acc[1][ct], 0, 0, 0);
        }

        __syncthreads();   // all vbuf/kb reads done; K(it+1)/V(it+1) loads landed
        if (it + 1 < 32) {
            writeV();      // vbuf <- V(it+1)
            __syncthreads();
        }
    }

    // ---- write partials: normalized O^T (f16) + m,l (f32) ----
    int slot = jq * 4 + n;
    if (quad == 0) {
#pragma unroll
        for (int mt = 0; mt < 2; mt++) {
            int i = i0 + w * 32 + mt * 16 + l16;
            g_ml[(slot * 2 + 0) * HW + i] = m_[mt];
            g_ml[(slot * 2 + 1) * HW + i] = l_[mt];
        }
    }
    f16* ob = g_opart + slot * CHW;
#pragma unroll
    for (int mt = 0; mt < 2; mt++) {
        int ig = i0 + w * 32 + mt * 16 + l16;
        float inv = (l_[mt] > 1e-30f) ? 1.0f / l_[mt] : 0.f;
#pragma unroll
        for (int ct = 0; ct < 16; ct++)
#pragma unroll
            for (int r = 0; r < 4; r++) {
                int c = ct * 16 + quad * 4 + r;
                ob[c * HW + ig] = (f16)(o_acc[mt][ct][r] * inv);
            }
    }
}

// ---------------- kernel 4: merge 4 j-quarters + residual + store ----------------
__global__ __launch_bounds__(256) void k_combine(
    const void* __restrict__ xv, const void* __restrict__ gv, void* __restrict__ outv)
{
    int mode = g_mode[0];
    float gam = fin0(mode ? ((const float*)gv)[0] : bf2f(((const ushort_t*)gv)[0]));
    int n = blockIdx.y;
    int base = blockIdx.x * 1024;
#pragma unroll
    for (int e = 0; e < 4; ++e) {
        int off = base + e * 256 + threadIdx.x;
        int i = off & (HW - 1);
        float m = -1e30f;
        float ms[4], ls[4];
#pragma unroll
        for (int s = 0; s < 4; ++s) {
            int slot = s * 4 + n;
            ms[s] = g_ml[(slot * 2 + 0) * HW + i];
            ls[s] = g_ml[(slot * 2 + 1) * HW + i];
            m = fmaxf(m, ms[s]);
        }
        float num = 0.f, den = 0.f;
#pragma unroll
        for (int s = 0; s < 4; ++s) {
            int slot = s * 4 + n;
            float wgt = __builtin_amdgcn_exp2f((ms[s] - m) * L2E) * ls[s];
            num += wgt * (float)((const f16*)g_opart)[slot * CHW + off];
            den += wgt;
        }
        float o = (den > 1e-30f) ? num / den : 0.f;
        if (mode == 0) {
            float xvv = bf2f(((const ushort_t*)xv)[n * CHW + off]);
            ((ushort_t*)outv)[n * CHW + off] = f2bf(fin0(xvv + gam * o));
        } else {
            float xvv = ((const float*)xv)[n * CHW + off];
            ((float*)outv)[n * CHW + off] = fin0(xvv + gam * o);
        }
    }
}

extern "C" void kernel_launch(void* const* d_in, const int* in_sizes, int n_in,
                              void* d_out, int out_size, void* d_ws, size_t ws_size,
                              hipStream_t stream) {
    (void)d_ws; (void)ws_size;
    bool ok = (n_in == 8) &&
              in_sizes[0] == 4 * CHW &&
              in_sizes[1] == C_DIM * C_DIM && in_sizes[2] == C_DIM &&
              in_sizes[3] == C_DIM * C_DIM && in_sizes[4] == C_DIM &&
              in_sizes[5] == C_DIM * C_DIM && in_sizes[6] == C_DIM &&
              in_sizes[7] == 1 && out_size == 4 * CHW;
    if (!ok) {
        hipLaunchKernelGGL(k_sentinel, dim3((out_size + 255) / 256), dim3(256), 0, stream,
                           (ushort_t*)d_out, out_size);
        return;
    }
    hipLaunchKernelGGL(k_probe, dim3(1), dim3(64), 0, stream, d_in[0]);
    hipLaunchKernelGGL(k_transpose, dim3(64, 4, 4), dim3(256), 0, stream, d_in[0]);
    hipLaunchKernelGGL(k_proj, dim3(32, 6, 4), dim3(256), 0, stream,
                       d_in[1], d_in[2], d_in[3], d_in[4], d_in[5], d_in[6]);
    hipLaunchKernelGGL(k_attn, dim3(512), dim3(256), 0, stream);
    hipLaunchKernelGGL(k_combine, dim3(CHW / 1024, 4), dim3(256), 0, stream,
                       d_in[0], d_in[7], d_out);
}